// Round 11
// baseline (371.583 us; speedup 1.0000x reference)
//
#include <hip/hip_runtime.h>
#include <math.h>

#define Bn 4
#define Tn 12
#define Nn 512
#define Dn 128
#define Ln 4
#define Hn 64
#define NNe (Nn*Nn)

typedef __attribute__((ext_vector_type(8))) short short8;
typedef __attribute__((ext_vector_type(4))) float f32x4;

__device__ __forceinline__ unsigned short f2bf(float f) {
    unsigned int u = __float_as_uint(f);
    unsigned int r = (u + 0x7FFF + ((u >> 16) & 1)) >> 16;   // RNE
    return (unsigned short)r;
}
__device__ __forceinline__ float bf2f(unsigned short s) {
    return __uint_as_float(((unsigned int)s) << 16);
}

// ============ K1: fused encoder x -> h -> agg -> sp/tp, with inline L2 warm ============
// R9 body + (a) inline prefetch preamble (replaces k_warm dispatch: same MLP burst at
// t=0, no extra dispatch), (b) launch_bounds(256,4): cap 128 VGPR -> 4 blocks/CU
// (R10: VGPR=196 capped occupancy at 2 waves/SIMD; body VALU needs only ~5.6us).
__global__ __launch_bounds__(256, 4) void k_enc(
    const float* __restrict__ x, const float* __restrict__ W1, const float* __restrict__ b1,
    const float* __restrict__ W2, const float* __restrict__ b2,
    const float* __restrict__ Ws1, const float* __restrict__ bs1,
    unsigned short* __restrict__ spb, unsigned short* __restrict__ tpb,
    unsigned int* __restrict__ maxslot, float* __restrict__ sink)
{
    __shared__ float hl[2*Ln*Hn];    // [row][lag][64] = 2 KB
    __shared__ float agg[2*Dn];      // [row][128]     = 1 KB
    int tid = threadIdx.x;
    int bx = blockIdx.x;
    int wv = __builtin_amdgcn_readfirstlane(tid >> 6);
    int lane = tid & 63;
    if (bx == 0 && tid < Bn) maxslot[tid] = 0u;

    // --- inline warm: 1 x-slice f4 per thread (+1 weight f4 for low ids), summed ---
    float wsum;
    {
        int i = bx*256 + tid;              // 0..262143 covers all 16 used x slices
        int sl = i >> 14, o = i & 16383;
        int b = sl >> 2, lag = sl & 3;
        float4 v = ((const float4*)(x + ((size_t)(b*Tn + (Tn-1-lag))*Nn)*Dn))[o];
        wsum = v.x + v.y + v.z + v.w;
        if (i < 8192)        { float4 w = ((const float4*)W1)[i];        wsum += w.x+w.y+w.z+w.w; }
        else if (i < 16384)  { float4 w = ((const float4*)W2)[i-8192];   wsum += w.x+w.y+w.z+w.w; }
        else if (i < 24576)  { float4 w = ((const float4*)Ws1)[i-16384]; wsum += w.x+w.y+w.z+w.w; }
    }

    int r0g = bx * 2;                       // 2 rows, never straddles a batch
    int bb = r0g >> 9, n0 = r0g & 511;

    // --- A: wave = lag; lane = h-channel; x rows via wave-uniform (scalar) loads ---
    {
        int lag = wv;
        const float* xr = x + ((size_t)(bb*Tn + (Tn-1-lag))*Nn + n0) * Dn;
        const float* Wp = W1 + (size_t)lag*Dn*Hn;
        float acc0 = 0.f, acc1 = 0.f;
        for (int d4 = 0; d4 < 32; ++d4) {
            float4 xv0 = *(const float4*)(xr + d4*4);          // uniform -> s_load
            float4 xv1 = *(const float4*)(xr + Dn + d4*4);
            #pragma unroll
            for (int u = 0; u < 4; ++u) {
                float w = Wp[(d4*4+u)*Hn + lane];              // coalesced
                acc0 += ((const float*)&xv0)[u]*w;
                acc1 += ((const float*)&xv1)[u]*w;
            }
        }
        float bv = b1[lag*Hn + lane];
        hl[(0*4 + lag)*64 + lane] = fmaxf(acc0+bv, 0.f);
        hl[(1*4 + lag)*64 + lane] = fmaxf(acc1+bv, 0.f);
    }
    __syncthreads();

    // --- B: wave = (row, d-half); lane = d ---
    {
        int row = wv >> 1;
        int d   = (wv & 1)*64 + lane;
        float acc = 0.f;
        for (int l = 0; l < Ln; ++l) {
            const float* hp = hl + (row*4 + l)*64;
            const float* Wp = W2 + (size_t)l*Hn*Dn + d;
            for (int h4 = 0; h4 < 16; ++h4) {
                float4 hv = *(const float4*)(hp + h4*4);       // LDS broadcast
                #pragma unroll
                for (int u = 0; u < 4; ++u)
                    acc += ((const float*)&hv)[u] * Wp[(size_t)(h4*4+u)*Dn];
            }
        }
        float b2s = b2[d] + b2[Dn+d] + b2[2*Dn+d] + b2[3*Dn+d];
        agg[row*Dn + d] = 0.25f*(acc + b2s);
    }
    __syncthreads();

    // --- C: wave = (row, tgt); lane = k and k+64 ---
    {
        int row = wv >> 1;
        int tgt = wv & 1;
        float s0 = 0.f, s1 = 0.f;                               // k, k+64
        const float* a0 = agg + row*Dn;
        const float* Wb = Ws1 + (size_t)tgt*Dn*Dn + lane;      // rows [tgt*128, ...)
        for (int d4 = 0; d4 < 32; ++d4) {
            float4 av = *(const float4*)(a0 + d4*4);           // LDS broadcast
            #pragma unroll
            for (int u = 0; u < 4; ++u) {
                float a = ((const float*)&av)[u];
                s0 += a * Wb[(size_t)(d4*4+u)*Dn];             // coalesced
                s1 += a * Wb[(size_t)(d4*4+u)*Dn + 64];
            }
        }
        float bv0 = (tgt == 0) ? bs1[lane]      : 0.f;         // fold bs1 into sp
        float bv1 = (tgt == 0) ? bs1[lane + 64] : 0.f;
        unsigned short* dst = tgt ? tpb : spb;
        dst[(size_t)(r0g+row)*Dn + lane]      = f2bf(s0 + bv0);
        dst[(size_t)(r0g+row)*Dn + lane + 64] = f2bf(s1 + bv1);
    }

    if (wsum == 1234.5678f) sink[0] = wsum;   // consume warm loads (never true)
}

// ============ K2: pairwise scorer -> adj bf16 row-major + transposed ============
__global__ __launch_bounds__(256) void k_score(
    const unsigned short* __restrict__ spb, const unsigned short* __restrict__ tpb,
    const float* __restrict__ Ws2, const float* __restrict__ bs2,
    unsigned short* __restrict__ adj_b, unsigned short* __restrict__ adj_bt)
{
    __shared__ float spl[64*132];                     // 33 KB
    __shared__ unsigned short tplT[Dn*72];            // 18 KB
    int tid = threadIdx.x;
    int wv = __builtin_amdgcn_readfirstlane(tid >> 6);
    int lane = tid & 63;
    int bz = blockIdx.z;
    int i0b = blockIdx.y * 64, j0b = blockIdx.x * 64;
    const unsigned short* spr = spb + (size_t)bz*Nn*Dn;
    const unsigned short* tpr = tpb + (size_t)bz*Nn*Dn;

    for (int v = tid; v < 1024; v += 256) {           // sp tile: bf16 -> fp32 LDS
        int row = v >> 4, c = v & 15;
        const unsigned short* src = spr + (size_t)(i0b+row)*Dn + c*8;
        ushort4 u0 = *(const ushort4*)src;
        ushort4 u1 = *(const ushort4*)(src + 4);
        float4 f0 = { bf2f(u0.x), bf2f(u0.y), bf2f(u0.z), bf2f(u0.w) };
        float4 f1 = { bf2f(u1.x), bf2f(u1.y), bf2f(u1.z), bf2f(u1.w) };
        *(float4*)&spl[row*132 + c*8]     = f0;
        *(float4*)&spl[row*132 + c*8 + 4] = f1;
    }
    {   // tp tile transposed, bf16
        int j = tid & 63, kq = tid >> 6;
        for (int p = 0; p < 4; ++p) {
            int k8 = p*4 + kq;
            short8 tv = *(const short8*)(tpr + (size_t)(j0b+j)*Dn + k8*8);
            #pragma unroll
            for (int t = 0; t < 8; ++t) tplT[(k8*8+t)*72 + j] = (unsigned short)tv[t];
        }
    }
    __syncthreads();

    int iq = lane >> 4, jq = lane & 15;
    int iw = wv*16 + iq*4;
    float acc[4][4] = {};
    for (int k8 = 0; k8 < 16; ++k8) {
        float4 wa = *(const float4*)(Ws2 + k8*8);     // uniform -> scalar path
        float4 wb = *(const float4*)(Ws2 + k8*8 + 4);
        float4 sA[4], sB[4];
        #pragma unroll
        for (int ii = 0; ii < 4; ++ii) {
            sA[ii] = *(const float4*)&spl[(iw+ii)*132 + k8*8];
            sB[ii] = *(const float4*)&spl[(iw+ii)*132 + k8*8 + 4];
        }
        ushort4 t4[8];
        #pragma unroll
        for (int kk = 0; kk < 8; ++kk) t4[kk] = *(const ushort4*)&tplT[(k8*8+kk)*72 + jq*4];
        #pragma unroll
        for (int kk = 0; kk < 8; ++kk) {
            float w = (kk < 4) ? ((const float*)&wa)[kk] : ((const float*)&wb)[kk-4];
            float tv0 = bf2f(t4[kk].x), tv1 = bf2f(t4[kk].y);
            float tv2 = bf2f(t4[kk].z), tv3 = bf2f(t4[kk].w);
            #pragma unroll
            for (int ii = 0; ii < 4; ++ii) {
                float s = (kk < 4) ? ((const float*)&sA[ii])[kk] : ((const float*)&sB[ii])[kk-4];
                acc[ii][0] += fmaxf(s + tv0, 0.f)*w;
                acc[ii][1] += fmaxf(s + tv1, 0.f)*w;
                acc[ii][2] += fmaxf(s + tv2, 0.f)*w;
                acc[ii][3] += fmaxf(s + tv3, 0.f)*w;
            }
        }
    }
    float bsv = bs2[0];
    int i0 = i0b + iw;
    int j0 = j0b + jq*4;
    float vals[4][4];
    #pragma unroll
    for (int ii = 0; ii < 4; ++ii) {
        int i = i0 + ii;
        #pragma unroll
        for (int jj = 0; jj < 4; ++jj) {
            float z = acc[ii][jj] + bsv;
            float sc = 1.f/(1.f + __expf(-z));
            int j = j0 + jj;
            vals[ii][jj] = (sc > 0.1f && i != j) ? sc : 0.f;
        }
    }
    size_t base = (size_t)bz << 18;
    #pragma unroll
    for (int ii = 0; ii < 4; ++ii) {
        ushort4 rv = make_ushort4(f2bf(vals[ii][0]), f2bf(vals[ii][1]),
                                  f2bf(vals[ii][2]), f2bf(vals[ii][3]));
        *(ushort4*)(adj_b + base + (size_t)(i0+ii)*Nn + j0) = rv;
    }
    #pragma unroll
    for (int jj = 0; jj < 4; ++jj) {
        ushort4 cv = make_ushort4(f2bf(vals[0][jj]), f2bf(vals[1][jj]),
                                  f2bf(vals[2][jj]), f2bf(vals[3][jj]));
        *(ushort4*)(adj_bt + base + (size_t)(j0+jj)*Nn + i0) = cv;
    }
}

// ============ K3: a2 = adj @ adj (MFMA, 64x64 tile, BK=64, reg double-buffer) ============
__global__ __launch_bounds__(256) void k_mm1(
    const unsigned short* __restrict__ adj_b, const unsigned short* __restrict__ adj_bt,
    unsigned short* __restrict__ a2b)
{
    __shared__ unsigned short Als[64*72];
    __shared__ unsigned short Bls[64*72];
    int tid = threadIdx.x;
    int wv = __builtin_amdgcn_readfirstlane(tid >> 6);
    int lane = tid & 63;
    int b = blockIdx.z, i0 = blockIdx.y*64, j0 = blockIdx.x*64;
    size_t base = (size_t)b << 18;
    const unsigned short* Ab = adj_b + base;
    const unsigned short* Bb = adj_bt + base;
    int wm = wv >> 1, wn = wv & 1;
    int m = lane & 15, q = lane >> 4;
    int sr = tid >> 2, sc = (tid & 3)*16;
    f32x4 acc[2][2];
    #pragma unroll
    for (int mt = 0; mt < 2; ++mt)
        #pragma unroll
        for (int nt = 0; nt < 2; ++nt) acc[mt][nt] = (f32x4){0.f,0.f,0.f,0.f};
    short8 pa0, pa1, pb0, pb1;
    pa0 = *(const short8*)(Ab + (size_t)(i0+sr)*Nn + sc);
    pa1 = *(const short8*)(Ab + (size_t)(i0+sr)*Nn + sc + 8);
    pb0 = *(const short8*)(Bb + (size_t)(j0+sr)*Nn + sc);
    pb1 = *(const short8*)(Bb + (size_t)(j0+sr)*Nn + sc + 8);
    for (int kt = 0; kt < 8; ++kt) {
        *(short8*)&Als[sr*72 + sc]     = pa0;
        *(short8*)&Als[sr*72 + sc + 8] = pa1;
        *(short8*)&Bls[sr*72 + sc]     = pb0;
        *(short8*)&Bls[sr*72 + sc + 8] = pb1;
        __syncthreads();
        if (kt < 7) {
            int k0 = (kt+1)*64;
            pa0 = *(const short8*)(Ab + (size_t)(i0+sr)*Nn + k0 + sc);
            pa1 = *(const short8*)(Ab + (size_t)(i0+sr)*Nn + k0 + sc + 8);
            pb0 = *(const short8*)(Bb + (size_t)(j0+sr)*Nn + k0 + sc);
            pb1 = *(const short8*)(Bb + (size_t)(j0+sr)*Nn + k0 + sc + 8);
        }
        #pragma unroll
        for (int ks = 0; ks < 2; ++ks) {
            short8 af[2], bg[2];
            #pragma unroll
            for (int mt = 0; mt < 2; ++mt) af[mt] = *(const short8*)&Als[(wm*32+mt*16+m)*72 + ks*32 + q*8];
            #pragma unroll
            for (int nt = 0; nt < 2; ++nt) bg[nt] = *(const short8*)&Bls[(wn*32+nt*16+m)*72 + ks*32 + q*8];
            #pragma unroll
            for (int mt = 0; mt < 2; ++mt)
                #pragma unroll
                for (int nt = 0; nt < 2; ++nt)
                    acc[mt][nt] = __builtin_amdgcn_mfma_f32_16x16x32_bf16(af[mt], bg[nt], acc[mt][nt], 0, 0, 0);
        }
        __syncthreads();
    }
    int col = lane & 15, rq = lane >> 4;
    #pragma unroll
    for (int mt = 0; mt < 2; ++mt)
        #pragma unroll
        for (int nt = 0; nt < 2; ++nt)
            #pragma unroll
            for (int reg = 0; reg < 4; ++reg) {
                int i = i0 + wm*32 + mt*16 + rq*4 + reg;
                int j = j0 + wn*32 + nt*16 + col;
                a2b[base + (size_t)i*Nn + j] = f2bf(acc[mt][nt][reg]);
            }
}

// ============ K4: out = adj + 0.5*a2 + 0.25*(a2@adj), + per-batch max ============
__global__ __launch_bounds__(256) void k_mm2(
    const unsigned short* __restrict__ adj_b, const unsigned short* __restrict__ adj_bt,
    const unsigned short* __restrict__ a2b,
    float* __restrict__ out, unsigned int* __restrict__ maxslot)
{
    __shared__ unsigned short Als[64*72];
    __shared__ unsigned short Bls[64*72];
    __shared__ float red[4];
    int tid = threadIdx.x;
    int wv = __builtin_amdgcn_readfirstlane(tid >> 6);
    int lane = tid & 63;
    int b = blockIdx.z, i0 = blockIdx.y*64, j0 = blockIdx.x*64;
    size_t base = (size_t)b << 18;
    const unsigned short* Ab = a2b + base;       // A = a2
    const unsigned short* Bb = adj_bt + base;    // B = adj (transposed layout)
    int wm = wv >> 1, wn = wv & 1;
    int m = lane & 15, q = lane >> 4;
    int sr = tid >> 2, sc = (tid & 3)*16;
    f32x4 acc[2][2];
    #pragma unroll
    for (int mt = 0; mt < 2; ++mt)
        #pragma unroll
        for (int nt = 0; nt < 2; ++nt) acc[mt][nt] = (f32x4){0.f,0.f,0.f,0.f};
    short8 pa0, pa1, pb0, pb1;
    pa0 = *(const short8*)(Ab + (size_t)(i0+sr)*Nn + sc);
    pa1 = *(const short8*)(Ab + (size_t)(i0+sr)*Nn + sc + 8);
    pb0 = *(const short8*)(Bb + (size_t)(j0+sr)*Nn + sc);
    pb1 = *(const short8*)(Bb + (size_t)(j0+sr)*Nn + sc + 8);
    for (int kt = 0; kt < 8; ++kt) {
        *(short8*)&Als[sr*72 + sc]     = pa0;
        *(short8*)&Als[sr*72 + sc + 8] = pa1;
        *(short8*)&Bls[sr*72 + sc]     = pb0;
        *(short8*)&Bls[sr*72 + sc + 8] = pb1;
        __syncthreads();
        if (kt < 7) {
            int k0 = (kt+1)*64;
            pa0 = *(const short8*)(Ab + (size_t)(i0+sr)*Nn + k0 + sc);
            pa1 = *(const short8*)(Ab + (size_t)(i0+sr)*Nn + k0 + sc + 8);
            pb0 = *(const short8*)(Bb + (size_t)(j0+sr)*Nn + k0 + sc);
            pb1 = *(const short8*)(Bb + (size_t)(j0+sr)*Nn + k0 + sc + 8);
        }
        #pragma unroll
        for (int ks = 0; ks < 2; ++ks) {
            short8 af[2], bg[2];
            #pragma unroll
            for (int mt = 0; mt < 2; ++mt) af[mt] = *(const short8*)&Als[(wm*32+mt*16+m)*72 + ks*32 + q*8];
            #pragma unroll
            for (int nt = 0; nt < 2; ++nt) bg[nt] = *(const short8*)&Bls[(wn*32+nt*16+m)*72 + ks*32 + q*8];
            #pragma unroll
            for (int mt = 0; mt < 2; ++mt)
                #pragma unroll
                for (int nt = 0; nt < 2; ++nt)
                    acc[mt][nt] = __builtin_amdgcn_mfma_f32_16x16x32_bf16(af[mt], bg[nt], acc[mt][nt], 0, 0, 0);
        }
        __syncthreads();
    }
    int col = lane & 15, rq = lane >> 4;
    float lmax = 0.f;
    const unsigned short* adjp = adj_b + base;
    #pragma unroll
    for (int mt = 0; mt < 2; ++mt)
        #pragma unroll
        for (int nt = 0; nt < 2; ++nt)
            #pragma unroll
            for (int reg = 0; reg < 4; ++reg) {
                int i = i0 + wm*32 + mt*16 + rq*4 + reg;
                int j = j0 + wn*32 + nt*16 + col;
                size_t off = (size_t)i*Nn + j;
                float e = bf2f(adjp[off]) + 0.5f*bf2f(Ab[off]) + 0.25f*acc[mt][nt][reg];
                out[base + off] = e;
                lmax = fmaxf(lmax, e);
            }
    #pragma unroll
    for (int s = 1; s < 64; s <<= 1) lmax = fmaxf(lmax, __shfl_xor(lmax, s, 64));
    if (lane == 0) red[wv] = lmax;
    __syncthreads();
    if (tid == 0) {
        float mx = fmaxf(fmaxf(red[0], red[1]), fmaxf(red[2], red[3]));
        atomicMax(maxslot + b, __float_as_uint(mx));
    }
}

// ============ K5: out /= (max + 1e-8) ============
__global__ __launch_bounds__(256) void k_norm(float* __restrict__ out,
                                              const unsigned int* __restrict__ maxslot)
{
    int idx = blockIdx.x*256 + threadIdx.x;   // float4 index; 65536 per batch
    int b = idx >> 16;
    float m = __uint_as_float(maxslot[b]);
    float inv = 1.f/(m + 1e-8f);
    float4* p = (float4*)out + idx;
    float4 v = *p;
    v.x *= inv; v.y *= inv; v.z *= inv; v.w *= inv;
    *p = v;
}

extern "C" void kernel_launch(void* const* d_in, const int* in_sizes, int n_in,
                              void* d_out, int out_size, void* d_ws, size_t ws_size,
                              hipStream_t stream) {
    const float* x   = (const float*)d_in[0];
    const float* W1  = (const float*)d_in[1];
    const float* b1  = (const float*)d_in[2];
    const float* W2  = (const float*)d_in[3];
    const float* b2  = (const float*)d_in[4];
    const float* Ws1 = (const float*)d_in[5];
    const float* bs1 = (const float*)d_in[6];
    const float* Ws2 = (const float*)d_in[7];
    const float* bs2 = (const float*)d_in[8];
    float* out = (float*)d_out;

    unsigned char* wsb = (unsigned char*)d_ws;
    unsigned short* spb    = (unsigned short*)(wsb);                    // 512 KB
    unsigned short* tpb    = (unsigned short*)(wsb + (512u<<10));       // 512 KB
    unsigned short* adj_b  = (unsigned short*)(wsb + (1024u<<10));      // 2 MB
    unsigned short* adj_bt = (unsigned short*)(wsb + (3072u<<10));      // 2 MB
    unsigned short* a2b    = (unsigned short*)(wsb + (5120u<<10));      // 2 MB
    unsigned int*   maxslot= (unsigned int*)(wsb + (7168u<<10));        // 16 B
    float*          sink   = (float*)(wsb + (7169u<<10));               // warm sink

    k_enc  <<<dim3(1024),    256, 0, stream>>>(x, W1, b1, W2, b2, Ws1, bs1, spb, tpb, maxslot, sink);
    k_score<<<dim3(8, 8, Bn),256, 0, stream>>>(spb, tpb, Ws2, bs2, adj_b, adj_bt);
    k_mm1  <<<dim3(8, 8, Bn),256, 0, stream>>>(adj_b, adj_bt, a2b);
    k_mm2  <<<dim3(8, 8, Bn),256, 0, stream>>>(adj_b, adj_bt, a2b, out, maxslot);
    k_norm <<<dim3(1024),    256, 0, stream>>>(out, maxslot);
}

// Round 12
// 170.316 us; speedup vs baseline: 2.1817x; 2.1817x over previous
//
#include <hip/hip_runtime.h>
#include <math.h>

#define Bn 4
#define Tn 12
#define Nn 512
#define Dn 128
#define Ln 4
#define Hn 64
#define NNe (Nn*Nn)

typedef __attribute__((ext_vector_type(8))) short short8;
typedef __attribute__((ext_vector_type(4))) float f32x4;

__device__ __forceinline__ unsigned short f2bf(float f) {
    unsigned int u = __float_as_uint(f);
    unsigned int r = (u + 0x7FFF + ((u >> 16) & 1)) >> 16;   // RNE
    return (unsigned short)r;
}
__device__ __forceinline__ float bf2f(unsigned short s) {
    return __uint_as_float(((unsigned int)s) << 16);
}

// ============ K1a: h = relu(x_lag @ W1[l] + b1) -> bf16 [row][lag][64] ============
// GEMM-style: W1[lag] (32KB) + x-tile (8KB) cooperatively staged in LDS (8 coalesced
// float4/thread, one latency) -- replaces 640 serial 4B loads/wave (R6-R10 failure)
// AND doubles as the cold-L2 warm (drops k_warm dispatch).
__global__ __launch_bounds__(256) void k_enc_a(
    const float* __restrict__ x, const float* __restrict__ W1, const float* __restrict__ b1,
    unsigned short* __restrict__ hb, unsigned int* __restrict__ maxslot)
{
    __shared__ float wls[Dn*Hn];     // 32 KB
    __shared__ float xls[16*Dn];     // 8 KB
    int tid = threadIdx.x;
    int lag = blockIdx.y;
    int r0  = blockIdx.x * 16;       // 16 rows, never straddles a batch
    if (blockIdx.x == 0 && lag == 0 && tid < Bn) maxslot[tid] = 0u;
    int bb = r0 >> 9, n0 = r0 & 511;

    for (int v = tid; v < 2048; v += 256)                 // W1[lag]: 2048 float4
        ((float4*)wls)[v] = ((const float4*)(W1 + (size_t)lag*Dn*Hn))[v];
    {
        const float4* xsrc = (const float4*)(x + ((size_t)(bb*Tn + (Tn-1-lag))*Nn + n0)*Dn);
        for (int v = tid; v < 512; v += 256)              // 16 contiguous rows: 512 float4
            ((float4*)xls)[v] = xsrc[v];
    }
    __syncthreads();

    int row = tid >> 4, colq = (tid & 15) * 4;            // 4 outputs/thread
    f32x4 acc = {0.f, 0.f, 0.f, 0.f};
    for (int d4 = 0; d4 < 32; ++d4) {
        float4 xv = *(const float4*)&xls[row*Dn + d4*4];  // 16-lane broadcast
        #pragma unroll
        for (int u = 0; u < 4; ++u) {
            float4 w4 = *(const float4*)&wls[(d4*4+u)*Hn + colq];
            float xu = ((const float*)&xv)[u];
            acc[0] += xu*w4.x; acc[1] += xu*w4.y; acc[2] += xu*w4.z; acc[3] += xu*w4.w;
        }
    }
    float4 bv = *(const float4*)(b1 + lag*Hn + colq);
    ushort4 o;
    o.x = f2bf(fmaxf(acc[0]+bv.x, 0.f)); o.y = f2bf(fmaxf(acc[1]+bv.y, 0.f));
    o.z = f2bf(fmaxf(acc[2]+bv.z, 0.f)); o.w = f2bf(fmaxf(acc[3]+bv.w, 0.f));
    *(ushort4*)(hb + ((size_t)(r0+row)*Ln + lag)*Hn + colq) = o;
}

// ============ K1b: agg = 0.25*(sum_l h_l @ W2[l] + sum b2) -> bf16 [row][128] ============
__global__ __launch_bounds__(256) void k_enc_b(
    const unsigned short* __restrict__ hb, const float* __restrict__ W2,
    const float* __restrict__ b2, unsigned short* __restrict__ aggb)
{
    __shared__ float wls[Hn*Dn];     // 32 KB (one lag at a time)
    __shared__ float hls[4*Ln*Hn];   // 4 KB: [row][lag][64] fp32
    int tid = threadIdx.x;
    int wv = __builtin_amdgcn_readfirstlane(tid >> 6);
    int lane = tid & 63;
    int r0 = blockIdx.x * 4;

    if (tid < 128) {                                      // 4 rows x 256 bf16, contiguous
        short8 v = ((const short8*)(hb + (size_t)r0*Ln*Hn))[tid];
        #pragma unroll
        for (int t = 0; t < 8; ++t) hls[tid*8 + t] = bf2f((unsigned short)v[t]);
    }

    int row = wv;                                         // wave = row; lane = col, col+64
    float acc0 = 0.f, acc1 = 0.f;
    for (int l = 0; l < Ln; ++l) {
        __syncthreads();                                  // prev compute done (covers hls 1st)
        for (int v = tid; v < 2048; v += 256)
            ((float4*)wls)[v] = ((const float4*)(W2 + (size_t)l*Hn*Dn))[v];
        __syncthreads();
        const float* hp = hls + row*(Ln*Hn) + l*Hn;
        for (int h4 = 0; h4 < 16; ++h4) {
            float4 hv = *(const float4*)(hp + h4*4);      // wave broadcast
            #pragma unroll
            for (int u = 0; u < 4; ++u) {
                float hu = ((const float*)&hv)[u];
                acc0 += hu * wls[(h4*4+u)*Dn + lane];
                acc1 += hu * wls[(h4*4+u)*Dn + lane + 64];
            }
        }
    }
    float b2s0 = b2[lane]    + b2[Dn+lane]    + b2[2*Dn+lane]    + b2[3*Dn+lane];
    float b2s1 = b2[lane+64] + b2[Dn+lane+64] + b2[2*Dn+lane+64] + b2[3*Dn+lane+64];
    aggb[(size_t)(r0+row)*Dn + lane]      = f2bf(0.25f*(acc0 + b2s0));
    aggb[(size_t)(r0+row)*Dn + lane + 64] = f2bf(0.25f*(acc1 + b2s1));
}

// ============ K1c: sp = agg@Ws1[:D]+bs1, tp = agg@Ws1[D:] -> bf16 ============
__global__ __launch_bounds__(256) void k_enc_c(
    const unsigned short* __restrict__ aggb, const float* __restrict__ Ws1,
    const float* __restrict__ bs1,
    unsigned short* __restrict__ spb, unsigned short* __restrict__ tpb)
{
    __shared__ float wls[64*Dn];     // 32 KB (64 d-rows of Ws1 at a time)
    __shared__ float als[4*Dn];      // 2 KB: [row][128] fp32
    int tid = threadIdx.x;
    int wv = __builtin_amdgcn_readfirstlane(tid >> 6);
    int lane = tid & 63;
    int r0 = blockIdx.x * 4;

    if (tid < 64) {                                       // 4 rows x 128 bf16 contiguous
        short8 v = ((const short8*)(aggb + (size_t)r0*Dn))[tid];
        #pragma unroll
        for (int t = 0; t < 8; ++t) als[tid*8 + t] = bf2f((unsigned short)v[t]);
    }

    int row = wv;
    float s0 = 0.f, s1 = 0.f, t0 = 0.f, t1 = 0.f;
    for (int chunk = 0; chunk < 4; ++chunk) {             // {sp,tp} x {d-lo,d-hi}
        __syncthreads();
        for (int v = tid; v < 2048; v += 256)
            ((float4*)wls)[v] = ((const float4*)(Ws1 + (size_t)chunk*64*Dn))[v];
        __syncthreads();
        const float* ap = als + row*Dn + (chunk & 1)*64;
        if (chunk < 2) {
            for (int d = 0; d < 64; ++d) {
                float a = ap[d];                          // wave broadcast
                s0 += a * wls[d*Dn + lane];
                s1 += a * wls[d*Dn + lane + 64];
            }
        } else {
            for (int d = 0; d < 64; ++d) {
                float a = ap[d];
                t0 += a * wls[d*Dn + lane];
                t1 += a * wls[d*Dn + lane + 64];
            }
        }
    }
    size_t ro = (size_t)(r0 + row) * Dn;
    spb[ro + lane]      = f2bf(s0 + bs1[lane]);           // fold bs1 into sp
    spb[ro + lane + 64] = f2bf(s1 + bs1[lane + 64]);
    tpb[ro + lane]      = f2bf(t0);
    tpb[ro + lane + 64] = f2bf(t1);
}

// ============ K2: pairwise scorer -> adj bf16 row-major + transposed ============
__global__ __launch_bounds__(256) void k_score(
    const unsigned short* __restrict__ spb, const unsigned short* __restrict__ tpb,
    const float* __restrict__ Ws2, const float* __restrict__ bs2,
    unsigned short* __restrict__ adj_b, unsigned short* __restrict__ adj_bt)
{
    __shared__ float spl[64*132];                     // 33 KB
    __shared__ unsigned short tplT[Dn*72];            // 18 KB
    int tid = threadIdx.x;
    int wv = __builtin_amdgcn_readfirstlane(tid >> 6);
    int lane = tid & 63;
    int bz = blockIdx.z;
    int i0b = blockIdx.y * 64, j0b = blockIdx.x * 64;
    const unsigned short* spr = spb + (size_t)bz*Nn*Dn;
    const unsigned short* tpr = tpb + (size_t)bz*Nn*Dn;

    for (int v = tid; v < 1024; v += 256) {           // sp tile: bf16 -> fp32 LDS
        int row = v >> 4, c = v & 15;
        const unsigned short* src = spr + (size_t)(i0b+row)*Dn + c*8;
        ushort4 u0 = *(const ushort4*)src;
        ushort4 u1 = *(const ushort4*)(src + 4);
        float4 f0 = { bf2f(u0.x), bf2f(u0.y), bf2f(u0.z), bf2f(u0.w) };
        float4 f1 = { bf2f(u1.x), bf2f(u1.y), bf2f(u1.z), bf2f(u1.w) };
        *(float4*)&spl[row*132 + c*8]     = f0;
        *(float4*)&spl[row*132 + c*8 + 4] = f1;
    }
    {   // tp tile transposed, bf16
        int j = tid & 63, kq = tid >> 6;
        for (int p = 0; p < 4; ++p) {
            int k8 = p*4 + kq;
            short8 tv = *(const short8*)(tpr + (size_t)(j0b+j)*Dn + k8*8);
            #pragma unroll
            for (int t = 0; t < 8; ++t) tplT[(k8*8+t)*72 + j] = (unsigned short)tv[t];
        }
    }
    __syncthreads();

    int iq = lane >> 4, jq = lane & 15;
    int iw = wv*16 + iq*4;
    float acc[4][4] = {};
    for (int k8 = 0; k8 < 16; ++k8) {
        float4 wa = *(const float4*)(Ws2 + k8*8);     // uniform -> scalar path
        float4 wb = *(const float4*)(Ws2 + k8*8 + 4);
        float4 sA[4], sB[4];
        #pragma unroll
        for (int ii = 0; ii < 4; ++ii) {
            sA[ii] = *(const float4*)&spl[(iw+ii)*132 + k8*8];
            sB[ii] = *(const float4*)&spl[(iw+ii)*132 + k8*8 + 4];
        }
        ushort4 t4[8];
        #pragma unroll
        for (int kk = 0; kk < 8; ++kk) t4[kk] = *(const ushort4*)&tplT[(k8*8+kk)*72 + jq*4];
        #pragma unroll
        for (int kk = 0; kk < 8; ++kk) {
            float w = (kk < 4) ? ((const float*)&wa)[kk] : ((const float*)&wb)[kk-4];
            float tv0 = bf2f(t4[kk].x), tv1 = bf2f(t4[kk].y);
            float tv2 = bf2f(t4[kk].z), tv3 = bf2f(t4[kk].w);
            #pragma unroll
            for (int ii = 0; ii < 4; ++ii) {
                float s = (kk < 4) ? ((const float*)&sA[ii])[kk] : ((const float*)&sB[ii])[kk-4];
                acc[ii][0] += fmaxf(s + tv0, 0.f)*w;
                acc[ii][1] += fmaxf(s + tv1, 0.f)*w;
                acc[ii][2] += fmaxf(s + tv2, 0.f)*w;
                acc[ii][3] += fmaxf(s + tv3, 0.f)*w;
            }
        }
    }
    float bsv = bs2[0];
    int i0 = i0b + iw;
    int j0 = j0b + jq*4;
    float vals[4][4];
    #pragma unroll
    for (int ii = 0; ii < 4; ++ii) {
        int i = i0 + ii;
        #pragma unroll
        for (int jj = 0; jj < 4; ++jj) {
            float z = acc[ii][jj] + bsv;
            float sc = 1.f/(1.f + __expf(-z));
            int j = j0 + jj;
            vals[ii][jj] = (sc > 0.1f && i != j) ? sc : 0.f;
        }
    }
    size_t base = (size_t)bz << 18;
    #pragma unroll
    for (int ii = 0; ii < 4; ++ii) {
        ushort4 rv = make_ushort4(f2bf(vals[ii][0]), f2bf(vals[ii][1]),
                                  f2bf(vals[ii][2]), f2bf(vals[ii][3]));
        *(ushort4*)(adj_b + base + (size_t)(i0+ii)*Nn + j0) = rv;
    }
    #pragma unroll
    for (int jj = 0; jj < 4; ++jj) {
        ushort4 cv = make_ushort4(f2bf(vals[0][jj]), f2bf(vals[1][jj]),
                                  f2bf(vals[2][jj]), f2bf(vals[3][jj]));
        *(ushort4*)(adj_bt + base + (size_t)(j0+jj)*Nn + i0) = cv;
    }
}

// ============ K3: a2 = adj @ adj (MFMA, 64x64 tile, BK=64, reg double-buffer) ============
__global__ __launch_bounds__(256) void k_mm1(
    const unsigned short* __restrict__ adj_b, const unsigned short* __restrict__ adj_bt,
    unsigned short* __restrict__ a2b)
{
    __shared__ unsigned short Als[64*72];
    __shared__ unsigned short Bls[64*72];
    int tid = threadIdx.x;
    int wv = __builtin_amdgcn_readfirstlane(tid >> 6);
    int lane = tid & 63;
    int b = blockIdx.z, i0 = blockIdx.y*64, j0 = blockIdx.x*64;
    size_t base = (size_t)b << 18;
    const unsigned short* Ab = adj_b + base;
    const unsigned short* Bb = adj_bt + base;
    int wm = wv >> 1, wn = wv & 1;
    int m = lane & 15, q = lane >> 4;
    int sr = tid >> 2, sc = (tid & 3)*16;
    f32x4 acc[2][2];
    #pragma unroll
    for (int mt = 0; mt < 2; ++mt)
        #pragma unroll
        for (int nt = 0; nt < 2; ++nt) acc[mt][nt] = (f32x4){0.f,0.f,0.f,0.f};
    short8 pa0, pa1, pb0, pb1;
    pa0 = *(const short8*)(Ab + (size_t)(i0+sr)*Nn + sc);
    pa1 = *(const short8*)(Ab + (size_t)(i0+sr)*Nn + sc + 8);
    pb0 = *(const short8*)(Bb + (size_t)(j0+sr)*Nn + sc);
    pb1 = *(const short8*)(Bb + (size_t)(j0+sr)*Nn + sc + 8);
    for (int kt = 0; kt < 8; ++kt) {
        *(short8*)&Als[sr*72 + sc]     = pa0;
        *(short8*)&Als[sr*72 + sc + 8] = pa1;
        *(short8*)&Bls[sr*72 + sc]     = pb0;
        *(short8*)&Bls[sr*72 + sc + 8] = pb1;
        __syncthreads();
        if (kt < 7) {
            int k0 = (kt+1)*64;
            pa0 = *(const short8*)(Ab + (size_t)(i0+sr)*Nn + k0 + sc);
            pa1 = *(const short8*)(Ab + (size_t)(i0+sr)*Nn + k0 + sc + 8);
            pb0 = *(const short8*)(Bb + (size_t)(j0+sr)*Nn + k0 + sc);
            pb1 = *(const short8*)(Bb + (size_t)(j0+sr)*Nn + k0 + sc + 8);
        }
        #pragma unroll
        for (int ks = 0; ks < 2; ++ks) {
            short8 af[2], bg[2];
            #pragma unroll
            for (int mt = 0; mt < 2; ++mt) af[mt] = *(const short8*)&Als[(wm*32+mt*16+m)*72 + ks*32 + q*8];
            #pragma unroll
            for (int nt = 0; nt < 2; ++nt) bg[nt] = *(const short8*)&Bls[(wn*32+nt*16+m)*72 + ks*32 + q*8];
            #pragma unroll
            for (int mt = 0; mt < 2; ++mt)
                #pragma unroll
                for (int nt = 0; nt < 2; ++nt)
                    acc[mt][nt] = __builtin_amdgcn_mfma_f32_16x16x32_bf16(af[mt], bg[nt], acc[mt][nt], 0, 0, 0);
        }
        __syncthreads();
    }
    int col = lane & 15, rq = lane >> 4;
    #pragma unroll
    for (int mt = 0; mt < 2; ++mt)
        #pragma unroll
        for (int nt = 0; nt < 2; ++nt)
            #pragma unroll
            for (int reg = 0; reg < 4; ++reg) {
                int i = i0 + wm*32 + mt*16 + rq*4 + reg;
                int j = j0 + wn*32 + nt*16 + col;
                a2b[base + (size_t)i*Nn + j] = f2bf(acc[mt][nt][reg]);
            }
}

// ============ K4: out = adj + 0.5*a2 + 0.25*(a2@adj), + per-batch max ============
__global__ __launch_bounds__(256) void k_mm2(
    const unsigned short* __restrict__ adj_b, const unsigned short* __restrict__ adj_bt,
    const unsigned short* __restrict__ a2b,
    float* __restrict__ out, unsigned int* __restrict__ maxslot)
{
    __shared__ unsigned short Als[64*72];
    __shared__ unsigned short Bls[64*72];
    __shared__ float red[4];
    int tid = threadIdx.x;
    int wv = __builtin_amdgcn_readfirstlane(tid >> 6);
    int lane = tid & 63;
    int b = blockIdx.z, i0 = blockIdx.y*64, j0 = blockIdx.x*64;
    size_t base = (size_t)b << 18;
    const unsigned short* Ab = a2b + base;       // A = a2
    const unsigned short* Bb = adj_bt + base;    // B = adj (transposed layout)
    int wm = wv >> 1, wn = wv & 1;
    int m = lane & 15, q = lane >> 4;
    int sr = tid >> 2, sc = (tid & 3)*16;
    f32x4 acc[2][2];
    #pragma unroll
    for (int mt = 0; mt < 2; ++mt)
        #pragma unroll
        for (int nt = 0; nt < 2; ++nt) acc[mt][nt] = (f32x4){0.f,0.f,0.f,0.f};
    short8 pa0, pa1, pb0, pb1;
    pa0 = *(const short8*)(Ab + (size_t)(i0+sr)*Nn + sc);
    pa1 = *(const short8*)(Ab + (size_t)(i0+sr)*Nn + sc + 8);
    pb0 = *(const short8*)(Bb + (size_t)(j0+sr)*Nn + sc);
    pb1 = *(const short8*)(Bb + (size_t)(j0+sr)*Nn + sc + 8);
    for (int kt = 0; kt < 8; ++kt) {
        *(short8*)&Als[sr*72 + sc]     = pa0;
        *(short8*)&Als[sr*72 + sc + 8] = pa1;
        *(short8*)&Bls[sr*72 + sc]     = pb0;
        *(short8*)&Bls[sr*72 + sc + 8] = pb1;
        __syncthreads();
        if (kt < 7) {
            int k0 = (kt+1)*64;
            pa0 = *(const short8*)(Ab + (size_t)(i0+sr)*Nn + k0 + sc);
            pa1 = *(const short8*)(Ab + (size_t)(i0+sr)*Nn + k0 + sc + 8);
            pb0 = *(const short8*)(Bb + (size_t)(j0+sr)*Nn + k0 + sc);
            pb1 = *(const short8*)(Bb + (size_t)(j0+sr)*Nn + k0 + sc + 8);
        }
        #pragma unroll
        for (int ks = 0; ks < 2; ++ks) {
            short8 af[2], bg[2];
            #pragma unroll
            for (int mt = 0; mt < 2; ++mt) af[mt] = *(const short8*)&Als[(wm*32+mt*16+m)*72 + ks*32 + q*8];
            #pragma unroll
            for (int nt = 0; nt < 2; ++nt) bg[nt] = *(const short8*)&Bls[(wn*32+nt*16+m)*72 + ks*32 + q*8];
            #pragma unroll
            for (int mt = 0; mt < 2; ++mt)
                #pragma unroll
                for (int nt = 0; nt < 2; ++nt)
                    acc[mt][nt] = __builtin_amdgcn_mfma_f32_16x16x32_bf16(af[mt], bg[nt], acc[mt][nt], 0, 0, 0);
        }
        __syncthreads();
    }
    int col = lane & 15, rq = lane >> 4;
    float lmax = 0.f;
    const unsigned short* adjp = adj_b + base;
    #pragma unroll
    for (int mt = 0; mt < 2; ++mt)
        #pragma unroll
        for (int nt = 0; nt < 2; ++nt)
            #pragma unroll
            for (int reg = 0; reg < 4; ++reg) {
                int i = i0 + wm*32 + mt*16 + rq*4 + reg;
                int j = j0 + wn*32 + nt*16 + col;
                size_t off = (size_t)i*Nn + j;
                float e = bf2f(adjp[off]) + 0.5f*bf2f(Ab[off]) + 0.25f*acc[mt][nt][reg];
                out[base + off] = e;
                lmax = fmaxf(lmax, e);
            }
    #pragma unroll
    for (int s = 1; s < 64; s <<= 1) lmax = fmaxf(lmax, __shfl_xor(lmax, s, 64));
    if (lane == 0) red[wv] = lmax;
    __syncthreads();
    if (tid == 0) {
        float mx = fmaxf(fmaxf(red[0], red[1]), fmaxf(red[2], red[3]));
        atomicMax(maxslot + b, __float_as_uint(mx));
    }
}

// ============ K5: out /= (max + 1e-8) ============
__global__ __launch_bounds__(256) void k_norm(float* __restrict__ out,
                                              const unsigned int* __restrict__ maxslot)
{
    int idx = blockIdx.x*256 + threadIdx.x;   // float4 index; 65536 per batch
    int b = idx >> 16;
    float m = __uint_as_float(maxslot[b]);
    float inv = 1.f/(m + 1e-8f);
    float4* p = (float4*)out + idx;
    float4 v = *p;
    v.x *= inv; v.y *= inv; v.z *= inv; v.w *= inv;
    *p = v;
}

extern "C" void kernel_launch(void* const* d_in, const int* in_sizes, int n_in,
                              void* d_out, int out_size, void* d_ws, size_t ws_size,
                              hipStream_t stream) {
    const float* x   = (const float*)d_in[0];
    const float* W1  = (const float*)d_in[1];
    const float* b1  = (const float*)d_in[2];
    const float* W2  = (const float*)d_in[3];
    const float* b2  = (const float*)d_in[4];
    const float* Ws1 = (const float*)d_in[5];
    const float* bs1 = (const float*)d_in[6];
    const float* Ws2 = (const float*)d_in[7];
    const float* bs2 = (const float*)d_in[8];
    float* out = (float*)d_out;

    unsigned char* wsb = (unsigned char*)d_ws;
    unsigned short* spb    = (unsigned short*)(wsb);                    // 512 KB
    unsigned short* tpb    = (unsigned short*)(wsb + (512u<<10));       // 512 KB
    unsigned short* adj_b  = (unsigned short*)(wsb + (1024u<<10));      // 2 MB
    unsigned short* adj_bt = (unsigned short*)(wsb + (3072u<<10));      // 2 MB
    unsigned short* a2b    = (unsigned short*)(wsb + (5120u<<10));      // 2 MB
    unsigned int*   maxslot= (unsigned int*)(wsb + (7168u<<10));        // 16 B
    unsigned short* hb     = (unsigned short*)(wsb + (7172u<<10));      // 1 MB  [row][lag][64]
    unsigned short* aggb   = (unsigned short*)(wsb + (8196u<<10));      // 512 KB [row][128]

    k_enc_a<<<dim3(128, 4),  256, 0, stream>>>(x, W1, b1, hb, maxslot);
    k_enc_b<<<dim3(512),     256, 0, stream>>>(hb, W2, b2, aggb);
    k_enc_c<<<dim3(512),     256, 0, stream>>>(aggb, Ws1, bs1, spb, tpb);
    k_score<<<dim3(8, 8, Bn),256, 0, stream>>>(spb, tpb, Ws2, bs2, adj_b, adj_bt);
    k_mm1  <<<dim3(8, 8, Bn),256, 0, stream>>>(adj_b, adj_bt, a2b);
    k_mm2  <<<dim3(8, 8, Bn),256, 0, stream>>>(adj_b, adj_bt, a2b, out, maxslot);
    k_norm <<<dim3(1024),    256, 0, stream>>>(out, maxslot);
}

// Round 13
// 144.105 us; speedup vs baseline: 2.5786x; 1.1819x over previous
//
#include <hip/hip_runtime.h>
#include <math.h>

#define Bn 4
#define Tn 12
#define Nn 512
#define Dn 128
#define Ln 4
#define Hn 64
#define NNe (Nn*Nn)

typedef __attribute__((ext_vector_type(8))) short short8;
typedef __attribute__((ext_vector_type(4))) float f32x4;

__device__ __forceinline__ unsigned short f2bf(float f) {
    unsigned int u = __float_as_uint(f);
    unsigned int r = (u + 0x7FFF + ((u >> 16) & 1)) >> 16;   // RNE
    return (unsigned short)r;
}
__device__ __forceinline__ float bf2f(unsigned short s) {
    return __uint_as_float(((unsigned int)s) << 16);
}

// ============ K1: MFMA encoder: x -> h -> agg -> sp/tp in ONE kernel ============
// The encoder is 3 GEMMs; R6-R12 proved every VALU formulation lands at 45-66us
// (spill or serial loads). This reuses the k_mm1 MFMA pattern: bf16 tiles in LDS
// (B-operand transposed to [n][k], stride 136/264 = 4-bank row offset), AGPR
// accumulators, high-MLP coalesced staging (doubles as the cold-L2 warm).
// 64 blocks x 32 rows. Static LDS 60416 B.
__global__ __launch_bounds__(256) void k_enc(
    const float* __restrict__ x, const float* __restrict__ W1, const float* __restrict__ b1,
    const float* __restrict__ W2, const float* __restrict__ b2,
    const float* __restrict__ Ws1, const float* __restrict__ bs1,
    unsigned short* __restrict__ spb, unsigned short* __restrict__ tpb,
    unsigned int* __restrict__ maxslot)
{
    __shared__ __align__(16) unsigned char smem[60416];
    unsigned short* hA   = (unsigned short*)smem;            // [32][264] A-tile: h, K=256
    unsigned short* xA   = (unsigned short*)(smem + 16896);  // [32][136] A-tile: x (phase A)
    unsigned short* w1T  = (unsigned short*)(smem + 25600);  // [64][136] B-tile: W1^T (phase A)
    unsigned short* aggA = (unsigned short*)(smem + 16896);  // [32][136] A-tile: agg (over dead xA)
    unsigned short* w2T  = (unsigned short*)(smem + 25600);  // [64][264] B-tile: W2^T half (over w1T)
    unsigned short* wsT  = (unsigned short*)(smem + 25600);  // [128][136] B-tile: Ws1^T half (phase C)

    int tid = threadIdx.x;
    int wv = __builtin_amdgcn_readfirstlane(tid >> 6);
    int lane = tid & 63;
    int bx = blockIdx.x;
    if (bx == 0 && tid < Bn) maxslot[tid] = 0u;
    int r0 = bx * 32;                      // 32 rows, never straddles a batch
    int bb = r0 >> 9, n0 = r0 & 511;

    int wm = wv >> 1, wn = wv & 1;         // wave row-half / col-half
    int m = lane & 15, q = lane >> 4;      // A/B fragment lane mapping (m89-verified)
    int colL = lane & 15, rq = lane >> 4;  // C/D fragment lane mapping

    // ---------------- Phase A: h[r][lag*64+n] = relu(x_lag @ W1[lag] + b1) ----------------
    for (int lag = 0; lag < Ln; ++lag) {
        __syncthreads();                   // prev-lag fragment reads done before restage
        {   // stage x tile: 32 contiguous rows, fp32 -> bf16
            const float4* xs = (const float4*)(x + ((size_t)(bb*Tn + (Tn-1-lag))*Nn + n0)*Dn);
            for (int v = tid; v < 1024; v += 256) {
                float4 f = xs[v];
                int row = v >> 5, c4 = v & 31;
                ushort4 o = { f2bf(f.x), f2bf(f.y), f2bf(f.z), f2bf(f.w) };
                *(ushort4*)&xA[row*136 + c4*4] = o;
            }
        }
        {   // stage W1[lag]^T: [128][64] -> [n=64][k=128]
            const float4* ws = (const float4*)(W1 + (size_t)lag*Dn*Hn);
            for (int v = tid; v < 2048; v += 256) {
                float4 f = ws[v];
                int d = v >> 4, nb = (v & 15)*4;
                w1T[(nb+0)*136 + d] = f2bf(f.x);
                w1T[(nb+1)*136 + d] = f2bf(f.y);
                w1T[(nb+2)*136 + d] = f2bf(f.z);
                w1T[(nb+3)*136 + d] = f2bf(f.w);
            }
        }
        __syncthreads();
        f32x4 acc[2] = {{0.f,0.f,0.f,0.f},{0.f,0.f,0.f,0.f}};
        #pragma unroll
        for (int ks = 0; ks < 4; ++ks) {
            short8 af = *(const short8*)&xA[(wm*16 + m)*136 + ks*32 + q*8];
            #pragma unroll
            for (int nt = 0; nt < 2; ++nt) {
                short8 bg = *(const short8*)&w1T[(wn*32 + nt*16 + m)*136 + ks*32 + q*8];
                acc[nt] = __builtin_amdgcn_mfma_f32_16x16x32_bf16(af, bg, acc[nt], 0, 0, 0);
            }
        }
        #pragma unroll
        for (int nt = 0; nt < 2; ++nt) {
            int ncol = wn*32 + nt*16 + colL;
            float bv = b1[lag*Hn + ncol];
            #pragma unroll
            for (int reg = 0; reg < 4; ++reg) {
                int rowL = wm*16 + rq*4 + reg;
                hA[rowL*264 + lag*64 + ncol] = f2bf(fmaxf(acc[nt][reg] + bv, 0.f));
            }
        }
    }
    __syncthreads();                       // hA complete; w1T/xA dead

    // ------------- Phase B: agg = 0.25*(h @ [W2 stacked] + sum_l b2[l]) -------------
    for (int h2 = 0; h2 < 2; ++h2) {       // two 64-col halves of agg
        if (h2) __syncthreads();           // h2=0 fragment reads done before restage
        for (int v = tid; v < 4096; v += 256) {    // stage W2^T half: [k=256][64cols]
            int r = v >> 4;                        // k = l*64+hh
            int c4b = (v & 15)*4;
            float4 f = ((const float4*)W2)[r*32 + h2*16 + (v & 15)];
            w2T[(c4b+0)*264 + r] = f2bf(f.x);
            w2T[(c4b+1)*264 + r] = f2bf(f.y);
            w2T[(c4b+2)*264 + r] = f2bf(f.z);
            w2T[(c4b+3)*264 + r] = f2bf(f.w);
        }
        __syncthreads();
        f32x4 acc[2] = {{0.f,0.f,0.f,0.f},{0.f,0.f,0.f,0.f}};
        #pragma unroll
        for (int ks = 0; ks < 8; ++ks) {
            short8 af = *(const short8*)&hA[(wm*16 + m)*264 + ks*32 + q*8];
            #pragma unroll
            for (int nt = 0; nt < 2; ++nt) {
                short8 bg = *(const short8*)&w2T[(wn*32 + nt*16 + m)*264 + ks*32 + q*8];
                acc[nt] = __builtin_amdgcn_mfma_f32_16x16x32_bf16(af, bg, acc[nt], 0, 0, 0);
            }
        }
        #pragma unroll
        for (int nt = 0; nt < 2; ++nt) {
            int n = h2*64 + wn*32 + nt*16 + colL;
            float b2s = b2[n] + b2[Dn+n] + b2[2*Dn+n] + b2[3*Dn+n];
            #pragma unroll
            for (int reg = 0; reg < 4; ++reg) {
                int rowL = wm*16 + rq*4 + reg;
                aggA[rowL*136 + n] = f2bf(0.25f*(acc[nt][reg] + b2s));
            }
        }
    }
    __syncthreads();                       // aggA complete; w2T dead

    // ------------- Phase C: sp = agg@Ws1[:D]+bs1 ; tp = agg@Ws1[D:] -------------
    for (int h3 = 0; h3 < 2; ++h3) {       // 0 = sp, 1 = tp
        if (h3) __syncthreads();
        for (int v = tid; v < 4096; v += 256) {    // stage Ws1^T half: [n=128][k=128]
            int r = v >> 5;                        // d (k index)
            int c4b = (v & 31)*4;
            float4 f = ((const float4*)Ws1)[(size_t)(h3*Dn + r)*32 + (v & 31)];
            wsT[(c4b+0)*136 + r] = f2bf(f.x);
            wsT[(c4b+1)*136 + r] = f2bf(f.y);
            wsT[(c4b+2)*136 + r] = f2bf(f.z);
            wsT[(c4b+3)*136 + r] = f2bf(f.w);
        }
        __syncthreads();
        f32x4 acc[4];
        #pragma unroll
        for (int nt = 0; nt < 4; ++nt) acc[nt] = (f32x4){0.f,0.f,0.f,0.f};
        #pragma unroll
        for (int ks = 0; ks < 4; ++ks) {
            short8 af = *(const short8*)&aggA[(wm*16 + m)*136 + ks*32 + q*8];
            #pragma unroll
            for (int nt = 0; nt < 4; ++nt) {
                short8 bg = *(const short8*)&wsT[(wn*64 + nt*16 + m)*136 + ks*32 + q*8];
                acc[nt] = __builtin_amdgcn_mfma_f32_16x16x32_bf16(af, bg, acc[nt], 0, 0, 0);
            }
        }
        unsigned short* dst = h3 ? tpb : spb;
        #pragma unroll
        for (int nt = 0; nt < 4; ++nt) {
            int n = wn*64 + nt*16 + colL;
            float bv = h3 ? 0.f : bs1[n];          // fold bs1 into sp
            #pragma unroll
            for (int reg = 0; reg < 4; ++reg) {
                int rowG = r0 + wm*16 + rq*4 + reg;
                dst[(size_t)rowG*Dn + n] = f2bf(acc[nt][reg] + bv);
            }
        }
    }
}

// ============ K2: pairwise scorer -> adj bf16 row-major + transposed ============
__global__ __launch_bounds__(256) void k_score(
    const unsigned short* __restrict__ spb, const unsigned short* __restrict__ tpb,
    const float* __restrict__ Ws2, const float* __restrict__ bs2,
    unsigned short* __restrict__ adj_b, unsigned short* __restrict__ adj_bt)
{
    __shared__ float spl[64*132];                     // 33 KB
    __shared__ unsigned short tplT[Dn*72];            // 18 KB
    int tid = threadIdx.x;
    int wv = __builtin_amdgcn_readfirstlane(tid >> 6);
    int lane = tid & 63;
    int bz = blockIdx.z;
    int i0b = blockIdx.y * 64, j0b = blockIdx.x * 64;
    const unsigned short* spr = spb + (size_t)bz*Nn*Dn;
    const unsigned short* tpr = tpb + (size_t)bz*Nn*Dn;

    for (int v = tid; v < 1024; v += 256) {           // sp tile: bf16 -> fp32 LDS
        int row = v >> 4, c = v & 15;
        const unsigned short* src = spr + (size_t)(i0b+row)*Dn + c*8;
        ushort4 u0 = *(const ushort4*)src;
        ushort4 u1 = *(const ushort4*)(src + 4);
        float4 f0 = { bf2f(u0.x), bf2f(u0.y), bf2f(u0.z), bf2f(u0.w) };
        float4 f1 = { bf2f(u1.x), bf2f(u1.y), bf2f(u1.z), bf2f(u1.w) };
        *(float4*)&spl[row*132 + c*8]     = f0;
        *(float4*)&spl[row*132 + c*8 + 4] = f1;
    }
    {   // tp tile transposed, bf16
        int j = tid & 63, kq = tid >> 6;
        for (int p = 0; p < 4; ++p) {
            int k8 = p*4 + kq;
            short8 tv = *(const short8*)(tpr + (size_t)(j0b+j)*Dn + k8*8);
            #pragma unroll
            for (int t = 0; t < 8; ++t) tplT[(k8*8+t)*72 + j] = (unsigned short)tv[t];
        }
    }
    __syncthreads();

    int iq = lane >> 4, jq = lane & 15;
    int iw = wv*16 + iq*4;
    float acc[4][4] = {};
    for (int k8 = 0; k8 < 16; ++k8) {
        float4 wa = *(const float4*)(Ws2 + k8*8);     // uniform -> scalar path
        float4 wb = *(const float4*)(Ws2 + k8*8 + 4);
        float4 sA[4], sB[4];
        #pragma unroll
        for (int ii = 0; ii < 4; ++ii) {
            sA[ii] = *(const float4*)&spl[(iw+ii)*132 + k8*8];
            sB[ii] = *(const float4*)&spl[(iw+ii)*132 + k8*8 + 4];
        }
        ushort4 t4[8];
        #pragma unroll
        for (int kk = 0; kk < 8; ++kk) t4[kk] = *(const ushort4*)&tplT[(k8*8+kk)*72 + jq*4];
        #pragma unroll
        for (int kk = 0; kk < 8; ++kk) {
            float w = (kk < 4) ? ((const float*)&wa)[kk] : ((const float*)&wb)[kk-4];
            float tv0 = bf2f(t4[kk].x), tv1 = bf2f(t4[kk].y);
            float tv2 = bf2f(t4[kk].z), tv3 = bf2f(t4[kk].w);
            #pragma unroll
            for (int ii = 0; ii < 4; ++ii) {
                float s = (kk < 4) ? ((const float*)&sA[ii])[kk] : ((const float*)&sB[ii])[kk-4];
                acc[ii][0] += fmaxf(s + tv0, 0.f)*w;
                acc[ii][1] += fmaxf(s + tv1, 0.f)*w;
                acc[ii][2] += fmaxf(s + tv2, 0.f)*w;
                acc[ii][3] += fmaxf(s + tv3, 0.f)*w;
            }
        }
    }
    float bsv = bs2[0];
    int i0 = i0b + iw;
    int j0 = j0b + jq*4;
    float vals[4][4];
    #pragma unroll
    for (int ii = 0; ii < 4; ++ii) {
        int i = i0 + ii;
        #pragma unroll
        for (int jj = 0; jj < 4; ++jj) {
            float z = acc[ii][jj] + bsv;
            float sc = 1.f/(1.f + __expf(-z));
            int j = j0 + jj;
            vals[ii][jj] = (sc > 0.1f && i != j) ? sc : 0.f;
        }
    }
    size_t base = (size_t)bz << 18;
    #pragma unroll
    for (int ii = 0; ii < 4; ++ii) {
        ushort4 rv = make_ushort4(f2bf(vals[ii][0]), f2bf(vals[ii][1]),
                                  f2bf(vals[ii][2]), f2bf(vals[ii][3]));
        *(ushort4*)(adj_b + base + (size_t)(i0+ii)*Nn + j0) = rv;
    }
    #pragma unroll
    for (int jj = 0; jj < 4; ++jj) {
        ushort4 cv = make_ushort4(f2bf(vals[0][jj]), f2bf(vals[1][jj]),
                                  f2bf(vals[2][jj]), f2bf(vals[3][jj]));
        *(ushort4*)(adj_bt + base + (size_t)(j0+jj)*Nn + i0) = cv;
    }
}

// ============ K3: a2 = adj @ adj (MFMA, 64x64 tile, BK=64, reg double-buffer) ============
__global__ __launch_bounds__(256) void k_mm1(
    const unsigned short* __restrict__ adj_b, const unsigned short* __restrict__ adj_bt,
    unsigned short* __restrict__ a2b)
{
    __shared__ unsigned short Als[64*72];
    __shared__ unsigned short Bls[64*72];
    int tid = threadIdx.x;
    int wv = __builtin_amdgcn_readfirstlane(tid >> 6);
    int lane = tid & 63;
    int b = blockIdx.z, i0 = blockIdx.y*64, j0 = blockIdx.x*64;
    size_t base = (size_t)b << 18;
    const unsigned short* Ab = adj_b + base;
    const unsigned short* Bb = adj_bt + base;
    int wm = wv >> 1, wn = wv & 1;
    int m = lane & 15, q = lane >> 4;
    int sr = tid >> 2, sc = (tid & 3)*16;
    f32x4 acc[2][2];
    #pragma unroll
    for (int mt = 0; mt < 2; ++mt)
        #pragma unroll
        for (int nt = 0; nt < 2; ++nt) acc[mt][nt] = (f32x4){0.f,0.f,0.f,0.f};
    short8 pa0, pa1, pb0, pb1;
    pa0 = *(const short8*)(Ab + (size_t)(i0+sr)*Nn + sc);
    pa1 = *(const short8*)(Ab + (size_t)(i0+sr)*Nn + sc + 8);
    pb0 = *(const short8*)(Bb + (size_t)(j0+sr)*Nn + sc);
    pb1 = *(const short8*)(Bb + (size_t)(j0+sr)*Nn + sc + 8);
    for (int kt = 0; kt < 8; ++kt) {
        *(short8*)&Als[sr*72 + sc]     = pa0;
        *(short8*)&Als[sr*72 + sc + 8] = pa1;
        *(short8*)&Bls[sr*72 + sc]     = pb0;
        *(short8*)&Bls[sr*72 + sc + 8] = pb1;
        __syncthreads();
        if (kt < 7) {
            int k0 = (kt+1)*64;
            pa0 = *(const short8*)(Ab + (size_t)(i0+sr)*Nn + k0 + sc);
            pa1 = *(const short8*)(Ab + (size_t)(i0+sr)*Nn + k0 + sc + 8);
            pb0 = *(const short8*)(Bb + (size_t)(j0+sr)*Nn + k0 + sc);
            pb1 = *(const short8*)(Bb + (size_t)(j0+sr)*Nn + k0 + sc + 8);
        }
        #pragma unroll
        for (int ks = 0; ks < 2; ++ks) {
            short8 af[2], bg[2];
            #pragma unroll
            for (int mt = 0; mt < 2; ++mt) af[mt] = *(const short8*)&Als[(wm*32+mt*16+m)*72 + ks*32 + q*8];
            #pragma unroll
            for (int nt = 0; nt < 2; ++nt) bg[nt] = *(const short8*)&Bls[(wn*32+nt*16+m)*72 + ks*32 + q*8];
            #pragma unroll
            for (int mt = 0; mt < 2; ++mt)
                #pragma unroll
                for (int nt = 0; nt < 2; ++nt)
                    acc[mt][nt] = __builtin_amdgcn_mfma_f32_16x16x32_bf16(af[mt], bg[nt], acc[mt][nt], 0, 0, 0);
        }
        __syncthreads();
    }
    int col = lane & 15, rq = lane >> 4;
    #pragma unroll
    for (int mt = 0; mt < 2; ++mt)
        #pragma unroll
        for (int nt = 0; nt < 2; ++nt)
            #pragma unroll
            for (int reg = 0; reg < 4; ++reg) {
                int i = i0 + wm*32 + mt*16 + rq*4 + reg;
                int j = j0 + wn*32 + nt*16 + col;
                a2b[base + (size_t)i*Nn + j] = f2bf(acc[mt][nt][reg]);
            }
}

// ============ K4: out = adj + 0.5*a2 + 0.25*(a2@adj), + per-batch max ============
__global__ __launch_bounds__(256) void k_mm2(
    const unsigned short* __restrict__ adj_b, const unsigned short* __restrict__ adj_bt,
    const unsigned short* __restrict__ a2b,
    float* __restrict__ out, unsigned int* __restrict__ maxslot)
{
    __shared__ unsigned short Als[64*72];
    __shared__ unsigned short Bls[64*72];
    __shared__ float red[4];
    int tid = threadIdx.x;
    int wv = __builtin_amdgcn_readfirstlane(tid >> 6);
    int lane = tid & 63;
    int b = blockIdx.z, i0 = blockIdx.y*64, j0 = blockIdx.x*64;
    size_t base = (size_t)b << 18;
    const unsigned short* Ab = a2b + base;       // A = a2
    const unsigned short* Bb = adj_bt + base;    // B = adj (transposed layout)
    int wm = wv >> 1, wn = wv & 1;
    int m = lane & 15, q = lane >> 4;
    int sr = tid >> 2, sc = (tid & 3)*16;
    f32x4 acc[2][2];
    #pragma unroll
    for (int mt = 0; mt < 2; ++mt)
        #pragma unroll
        for (int nt = 0; nt < 2; ++nt) acc[mt][nt] = (f32x4){0.f,0.f,0.f,0.f};
    short8 pa0, pa1, pb0, pb1;
    pa0 = *(const short8*)(Ab + (size_t)(i0+sr)*Nn + sc);
    pa1 = *(const short8*)(Ab + (size_t)(i0+sr)*Nn + sc + 8);
    pb0 = *(const short8*)(Bb + (size_t)(j0+sr)*Nn + sc);
    pb1 = *(const short8*)(Bb + (size_t)(j0+sr)*Nn + sc + 8);
    for (int kt = 0; kt < 8; ++kt) {
        *(short8*)&Als[sr*72 + sc]     = pa0;
        *(short8*)&Als[sr*72 + sc + 8] = pa1;
        *(short8*)&Bls[sr*72 + sc]     = pb0;
        *(short8*)&Bls[sr*72 + sc + 8] = pb1;
        __syncthreads();
        if (kt < 7) {
            int k0 = (kt+1)*64;
            pa0 = *(const short8*)(Ab + (size_t)(i0+sr)*Nn + k0 + sc);
            pa1 = *(const short8*)(Ab + (size_t)(i0+sr)*Nn + k0 + sc + 8);
            pb0 = *(const short8*)(Bb + (size_t)(j0+sr)*Nn + k0 + sc);
            pb1 = *(const short8*)(Bb + (size_t)(j0+sr)*Nn + k0 + sc + 8);
        }
        #pragma unroll
        for (int ks = 0; ks < 2; ++ks) {
            short8 af[2], bg[2];
            #pragma unroll
            for (int mt = 0; mt < 2; ++mt) af[mt] = *(const short8*)&Als[(wm*32+mt*16+m)*72 + ks*32 + q*8];
            #pragma unroll
            for (int nt = 0; nt < 2; ++nt) bg[nt] = *(const short8*)&Bls[(wn*32+nt*16+m)*72 + ks*32 + q*8];
            #pragma unroll
            for (int mt = 0; mt < 2; ++mt)
                #pragma unroll
                for (int nt = 0; nt < 2; ++nt)
                    acc[mt][nt] = __builtin_amdgcn_mfma_f32_16x16x32_bf16(af[mt], bg[nt], acc[mt][nt], 0, 0, 0);
        }
        __syncthreads();
    }
    int col = lane & 15, rq = lane >> 4;
    float lmax = 0.f;
    const unsigned short* adjp = adj_b + base;
    #pragma unroll
    for (int mt = 0; mt < 2; ++mt)
        #pragma unroll
        for (int nt = 0; nt < 2; ++nt)
            #pragma unroll
            for (int reg = 0; reg < 4; ++reg) {
                int i = i0 + wm*32 + mt*16 + rq*4 + reg;
                int j = j0 + wn*32 + nt*16 + col;
                size_t off = (size_t)i*Nn + j;
                float e = bf2f(adjp[off]) + 0.5f*bf2f(Ab[off]) + 0.25f*acc[mt][nt][reg];
                out[base + off] = e;
                lmax = fmaxf(lmax, e);
            }
    #pragma unroll
    for (int s = 1; s < 64; s <<= 1) lmax = fmaxf(lmax, __shfl_xor(lmax, s, 64));
    if (lane == 0) red[wv] = lmax;
    __syncthreads();
    if (tid == 0) {
        float mx = fmaxf(fmaxf(red[0], red[1]), fmaxf(red[2], red[3]));
        atomicMax(maxslot + b, __float_as_uint(mx));
    }
}

// ============ K5: out /= (max + 1e-8) ============
__global__ __launch_bounds__(256) void k_norm(float* __restrict__ out,
                                              const unsigned int* __restrict__ maxslot)
{
    int idx = blockIdx.x*256 + threadIdx.x;   // float4 index; 65536 per batch
    int b = idx >> 16;
    float m = __uint_as_float(maxslot[b]);
    float inv = 1.f/(m + 1e-8f);
    float4* p = (float4*)out + idx;
    float4 v = *p;
    v.x *= inv; v.y *= inv; v.z *= inv; v.w *= inv;
    *p = v;
}

extern "C" void kernel_launch(void* const* d_in, const int* in_sizes, int n_in,
                              void* d_out, int out_size, void* d_ws, size_t ws_size,
                              hipStream_t stream) {
    const float* x   = (const float*)d_in[0];
    const float* W1  = (const float*)d_in[1];
    const float* b1  = (const float*)d_in[2];
    const float* W2  = (const float*)d_in[3];
    const float* b2  = (const float*)d_in[4];
    const float* Ws1 = (const float*)d_in[5];
    const float* bs1 = (const float*)d_in[6];
    const float* Ws2 = (const float*)d_in[7];
    const float* bs2 = (const float*)d_in[8];
    float* out = (float*)d_out;

    unsigned char* wsb = (unsigned char*)d_ws;
    unsigned short* spb    = (unsigned short*)(wsb);                    // 512 KB
    unsigned short* tpb    = (unsigned short*)(wsb + (512u<<10));       // 512 KB
    unsigned short* adj_b  = (unsigned short*)(wsb + (1024u<<10));      // 2 MB
    unsigned short* adj_bt = (unsigned short*)(wsb + (3072u<<10));      // 2 MB
    unsigned short* a2b    = (unsigned short*)(wsb + (5120u<<10));      // 2 MB
    unsigned int*   maxslot= (unsigned int*)(wsb + (7168u<<10));        // 16 B

    k_enc  <<<dim3(64),      256, 0, stream>>>(x, W1, b1, W2, b2, Ws1, bs1, spb, tpb, maxslot);
    k_score<<<dim3(8, 8, Bn),256, 0, stream>>>(spb, tpb, Ws2, bs2, adj_b, adj_bt);
    k_mm1  <<<dim3(8, 8, Bn),256, 0, stream>>>(adj_b, adj_bt, a2b);
    k_mm2  <<<dim3(8, 8, Bn),256, 0, stream>>>(adj_b, adj_bt, a2b, out, maxslot);
    k_norm <<<dim3(1024),    256, 0, stream>>>(out, maxslot);
}

// Round 14
// 124.650 us; speedup vs baseline: 2.9810x; 1.1561x over previous
//
#include <hip/hip_runtime.h>
#include <math.h>

#define Bn 4
#define Tn 12
#define Nn 512
#define Dn 128
#define Ln 4
#define Hn 64
#define NNe (Nn*Nn)

typedef __attribute__((ext_vector_type(8))) short short8;
typedef __attribute__((ext_vector_type(4))) float f32x4;

__device__ __forceinline__ unsigned short f2bf(float f) {
    unsigned int u = __float_as_uint(f);
    unsigned int r = (u + 0x7FFF + ((u >> 16) & 1)) >> 16;   // RNE
    return (unsigned short)r;
}
__device__ __forceinline__ float bf2f(unsigned short s) {
    return __uint_as_float(((unsigned int)s) << 16);
}

// ============ K1a: h[r][lag*64+n] = relu(x_lag @ W1[lag] + b1[lag]) (MFMA) ============
// Grid (64,4): one (row-group, lag) per block -> 256 blocks, ONE sync pair.
// W transpose done in registers: 8 coalesced scalar reads -> one aligned b128 LDS
// write (8-phase minimum, no conflicts) -- R13's scalar transposed writes cost
// 2.04M conflict cycles.
__global__ __launch_bounds__(256) void k_enc_a(
    const float* __restrict__ x, const float* __restrict__ W1, const float* __restrict__ b1,
    unsigned short* __restrict__ hb, unsigned int* __restrict__ maxslot)
{
    __shared__ __align__(16) unsigned short xA[32*136];   // A-tile [m=32][k=128]
    __shared__ __align__(16) unsigned short w1T[64*136];  // B-tile [n=64][k=128]
    int tid = threadIdx.x;
    int rg = blockIdx.x, lag = blockIdx.y;
    if (rg == 0 && lag == 0 && tid < Bn) maxslot[tid] = 0u;
    int r0 = rg * 32;                     // 32 rows, never straddles a batch
    int bb = r0 >> 9, n0 = r0 & 511;

    {   // stage x tile: 32 contiguous rows fp32 -> bf16 (coalesced f4 reads)
        const float4* xs = (const float4*)(x + ((size_t)(bb*Tn + (Tn-1-lag))*Nn + n0)*Dn);
        for (int v = tid; v < 1024; v += 256) {
            float4 f = xs[v];
            int row = v >> 5, c4 = v & 31;
            ushort4 o = { f2bf(f.x), f2bf(f.y), f2bf(f.z), f2bf(f.w) };
            *(ushort4*)&xA[row*136 + c4*4] = o;
        }
    }
    {   // stage W1[lag]^T: thread owns (n, k-octet); 8 coalesced scalar reads + 1 b128 write
        int n = tid & 63, kq = tid >> 6;
        const float* Wp = W1 + (size_t)lag*Dn*Hn;
        #pragma unroll
        for (int r = 0; r < 4; ++r) {
            int k0 = (r*4 + kq)*8;
            unsigned short tmp[8];
            #pragma unroll
            for (int j = 0; j < 8; ++j) tmp[j] = f2bf(Wp[(size_t)(k0+j)*Hn + n]);
            *(short8*)&w1T[n*136 + k0] = *(const short8*)tmp;
        }
    }
    __syncthreads();

    int wv = __builtin_amdgcn_readfirstlane(tid >> 6);
    int lane = tid & 63;
    int wm = wv >> 1, wn = wv & 1;
    int m = lane & 15, q = lane >> 4;
    f32x4 acc[2] = {{0.f,0.f,0.f,0.f},{0.f,0.f,0.f,0.f}};
    #pragma unroll
    for (int ks = 0; ks < 4; ++ks) {
        short8 af = *(const short8*)&xA[(wm*16 + m)*136 + ks*32 + q*8];
        #pragma unroll
        for (int nt = 0; nt < 2; ++nt) {
            short8 bg = *(const short8*)&w1T[(wn*32 + nt*16 + m)*136 + ks*32 + q*8];
            acc[nt] = __builtin_amdgcn_mfma_f32_16x16x32_bf16(af, bg, acc[nt], 0, 0, 0);
        }
    }
    int colL = lane & 15, rq = lane >> 4;
    #pragma unroll
    for (int nt = 0; nt < 2; ++nt) {
        int ncol = wn*32 + nt*16 + colL;
        float bv = b1[lag*Hn + ncol];
        #pragma unroll
        for (int reg = 0; reg < 4; ++reg) {
            int rowL = wm*16 + rq*4 + reg;
            hb[(size_t)(r0+rowL)*256 + lag*64 + ncol] = f2bf(fmaxf(acc[nt][reg] + bv, 0.f));
        }
    }
}

// ============ K1b: agg = 0.25*(h @ W2stacked + sum_l b2[l]) (MFMA) ============
// Grid (64,2): (row-group, 64-col half) -> 128 blocks.
__global__ __launch_bounds__(256) void k_enc_b(
    const unsigned short* __restrict__ hb, const float* __restrict__ W2,
    const float* __restrict__ b2, unsigned short* __restrict__ aggb)
{
    __shared__ __align__(16) unsigned short hA[32*264];   // A-tile [m=32][k=256]
    __shared__ __align__(16) unsigned short w2T[64*264];  // B-tile [n=64][k=256]
    int tid = threadIdx.x;
    int rg = blockIdx.x, ch = blockIdx.y;
    int r0 = rg * 32;

    for (int v = tid; v < 1024; v += 256) {   // hA: straight bf16 copy, b128
        int row = v >> 5, c = v & 31;
        *(short8*)&hA[row*264 + c*8] = *(const short8*)(hb + (size_t)(r0+row)*256 + c*8);
    }
    {   // w2T: register transpose. W2 flat rows k = l*64+hh -> W2[k*128 + col]
        int n = tid & 63, kq = tid >> 6;
        #pragma unroll
        for (int r = 0; r < 8; ++r) {
            int k0 = (r*4 + kq)*8;
            unsigned short tmp[8];
            #pragma unroll
            for (int j = 0; j < 8; ++j) tmp[j] = f2bf(W2[(size_t)(k0+j)*Dn + ch*64 + n]);
            *(short8*)&w2T[n*264 + k0] = *(const short8*)tmp;
        }
    }
    __syncthreads();

    int wv = __builtin_amdgcn_readfirstlane(tid >> 6);
    int lane = tid & 63;
    int wm = wv >> 1, wn = wv & 1;
    int m = lane & 15, q = lane >> 4;
    f32x4 acc[2] = {{0.f,0.f,0.f,0.f},{0.f,0.f,0.f,0.f}};
    #pragma unroll
    for (int ks = 0; ks < 8; ++ks) {
        short8 af = *(const short8*)&hA[(wm*16 + m)*264 + ks*32 + q*8];
        #pragma unroll
        for (int nt = 0; nt < 2; ++nt) {
            short8 bg = *(const short8*)&w2T[(wn*32 + nt*16 + m)*264 + ks*32 + q*8];
            acc[nt] = __builtin_amdgcn_mfma_f32_16x16x32_bf16(af, bg, acc[nt], 0, 0, 0);
        }
    }
    int colL = lane & 15, rq = lane >> 4;
    #pragma unroll
    for (int nt = 0; nt < 2; ++nt) {
        int col = ch*64 + wn*32 + nt*16 + colL;
        float b2s = b2[col] + b2[Dn+col] + b2[2*Dn+col] + b2[3*Dn+col];
        #pragma unroll
        for (int reg = 0; reg < 4; ++reg) {
            int rowL = wm*16 + rq*4 + reg;
            aggb[(size_t)(r0+rowL)*Dn + col] = f2bf(0.25f*(acc[nt][reg] + b2s));
        }
    }
}

// ============ K1c: sp = agg@Ws1[:D]+bs1 ; tp = agg@Ws1[D:] (MFMA) ============
// Grid (64,2): (row-group, tgt) -> 128 blocks. N-tile = 128.
__global__ __launch_bounds__(256) void k_enc_c(
    const unsigned short* __restrict__ aggb, const float* __restrict__ Ws1,
    const float* __restrict__ bs1,
    unsigned short* __restrict__ spb, unsigned short* __restrict__ tpb)
{
    __shared__ __align__(16) unsigned short aggA[32*136];  // A-tile [m=32][k=128]
    __shared__ __align__(16) unsigned short wsT[128*136];  // B-tile [n=128][k=128]
    int tid = threadIdx.x;
    int rg = blockIdx.x, tgt = blockIdx.y;
    int r0 = rg * 32;

    for (int v = tid; v < 512; v += 256) {    // aggA: straight bf16 copy
        int row = v >> 4, c = v & 15;
        *(short8*)&aggA[row*136 + c*8] = *(const short8*)(aggb + (size_t)(r0+row)*Dn + c*8);
    }
    {   // wsT: register transpose of Ws1 rows [tgt*128 .. +128)
        int n = tid & 127, kq = tid >> 7;     // kq in 0..1
        #pragma unroll
        for (int r = 0; r < 8; ++r) {
            int k0 = (r*2 + kq)*8;
            unsigned short tmp[8];
            #pragma unroll
            for (int j = 0; j < 8; ++j)
                tmp[j] = f2bf(Ws1[(size_t)(tgt*Dn + k0 + j)*Dn + n]);
            *(short8*)&wsT[n*136 + k0] = *(const short8*)tmp;
        }
    }
    __syncthreads();

    int wv = __builtin_amdgcn_readfirstlane(tid >> 6);
    int lane = tid & 63;
    int wm = wv >> 1, wn = wv & 1;
    int m = lane & 15, q = lane >> 4;
    f32x4 acc[4];
    #pragma unroll
    for (int nt = 0; nt < 4; ++nt) acc[nt] = (f32x4){0.f,0.f,0.f,0.f};
    #pragma unroll
    for (int ks = 0; ks < 4; ++ks) {
        short8 af = *(const short8*)&aggA[(wm*16 + m)*136 + ks*32 + q*8];
        #pragma unroll
        for (int nt = 0; nt < 4; ++nt) {
            short8 bg = *(const short8*)&wsT[(wn*64 + nt*16 + m)*136 + ks*32 + q*8];
            acc[nt] = __builtin_amdgcn_mfma_f32_16x16x32_bf16(af, bg, acc[nt], 0, 0, 0);
        }
    }
    int colL = lane & 15, rq = lane >> 4;
    unsigned short* dst = tgt ? tpb : spb;
    #pragma unroll
    for (int nt = 0; nt < 4; ++nt) {
        int n = wn*64 + nt*16 + colL;
        float bv = tgt ? 0.f : bs1[n];        // fold bs1 into sp
        #pragma unroll
        for (int reg = 0; reg < 4; ++reg) {
            int rowG = r0 + wm*16 + rq*4 + reg;
            dst[(size_t)rowG*Dn + n] = f2bf(acc[nt][reg] + bv);
        }
    }
}

// ============ K2: pairwise scorer -> adj bf16 row-major + transposed ============
__global__ __launch_bounds__(256) void k_score(
    const unsigned short* __restrict__ spb, const unsigned short* __restrict__ tpb,
    const float* __restrict__ Ws2, const float* __restrict__ bs2,
    unsigned short* __restrict__ adj_b, unsigned short* __restrict__ adj_bt)
{
    __shared__ float spl[64*132];                     // 33 KB
    __shared__ unsigned short tplT[Dn*72];            // 18 KB
    int tid = threadIdx.x;
    int wv = __builtin_amdgcn_readfirstlane(tid >> 6);
    int lane = tid & 63;
    int bz = blockIdx.z;
    int i0b = blockIdx.y * 64, j0b = blockIdx.x * 64;
    const unsigned short* spr = spb + (size_t)bz*Nn*Dn;
    const unsigned short* tpr = tpb + (size_t)bz*Nn*Dn;

    for (int v = tid; v < 1024; v += 256) {           // sp tile: bf16 -> fp32 LDS
        int row = v >> 4, c = v & 15;
        const unsigned short* src = spr + (size_t)(i0b+row)*Dn + c*8;
        ushort4 u0 = *(const ushort4*)src;
        ushort4 u1 = *(const ushort4*)(src + 4);
        float4 f0 = { bf2f(u0.x), bf2f(u0.y), bf2f(u0.z), bf2f(u0.w) };
        float4 f1 = { bf2f(u1.x), bf2f(u1.y), bf2f(u1.z), bf2f(u1.w) };
        *(float4*)&spl[row*132 + c*8]     = f0;
        *(float4*)&spl[row*132 + c*8 + 4] = f1;
    }
    {   // tp tile transposed, bf16
        int j = tid & 63, kq = tid >> 6;
        for (int p = 0; p < 4; ++p) {
            int k8 = p*4 + kq;
            short8 tv = *(const short8*)(tpr + (size_t)(j0b+j)*Dn + k8*8);
            #pragma unroll
            for (int t = 0; t < 8; ++t) tplT[(k8*8+t)*72 + j] = (unsigned short)tv[t];
        }
    }
    __syncthreads();

    int iq = lane >> 4, jq = lane & 15;
    int iw = wv*16 + iq*4;
    float acc[4][4] = {};
    for (int k8 = 0; k8 < 16; ++k8) {
        float4 wa = *(const float4*)(Ws2 + k8*8);     // uniform -> scalar path
        float4 wb = *(const float4*)(Ws2 + k8*8 + 4);
        float4 sA[4], sB[4];
        #pragma unroll
        for (int ii = 0; ii < 4; ++ii) {
            sA[ii] = *(const float4*)&spl[(iw+ii)*132 + k8*8];
            sB[ii] = *(const float4*)&spl[(iw+ii)*132 + k8*8 + 4];
        }
        ushort4 t4[8];
        #pragma unroll
        for (int kk = 0; kk < 8; ++kk) t4[kk] = *(const ushort4*)&tplT[(k8*8+kk)*72 + jq*4];
        #pragma unroll
        for (int kk = 0; kk < 8; ++kk) {
            float w = (kk < 4) ? ((const float*)&wa)[kk] : ((const float*)&wb)[kk-4];
            float tv0 = bf2f(t4[kk].x), tv1 = bf2f(t4[kk].y);
            float tv2 = bf2f(t4[kk].z), tv3 = bf2f(t4[kk].w);
            #pragma unroll
            for (int ii = 0; ii < 4; ++ii) {
                float s = (kk < 4) ? ((const float*)&sA[ii])[kk] : ((const float*)&sB[ii])[kk-4];
                acc[ii][0] += fmaxf(s + tv0, 0.f)*w;
                acc[ii][1] += fmaxf(s + tv1, 0.f)*w;
                acc[ii][2] += fmaxf(s + tv2, 0.f)*w;
                acc[ii][3] += fmaxf(s + tv3, 0.f)*w;
            }
        }
    }
    float bsv = bs2[0];
    int i0 = i0b + iw;
    int j0 = j0b + jq*4;
    float vals[4][4];
    #pragma unroll
    for (int ii = 0; ii < 4; ++ii) {
        int i = i0 + ii;
        #pragma unroll
        for (int jj = 0; jj < 4; ++jj) {
            float z = acc[ii][jj] + bsv;
            float sc = 1.f/(1.f + __expf(-z));
            int j = j0 + jj;
            vals[ii][jj] = (sc > 0.1f && i != j) ? sc : 0.f;
        }
    }
    size_t base = (size_t)bz << 18;
    #pragma unroll
    for (int ii = 0; ii < 4; ++ii) {
        ushort4 rv = make_ushort4(f2bf(vals[ii][0]), f2bf(vals[ii][1]),
                                  f2bf(vals[ii][2]), f2bf(vals[ii][3]));
        *(ushort4*)(adj_b + base + (size_t)(i0+ii)*Nn + j0) = rv;
    }
    #pragma unroll
    for (int jj = 0; jj < 4; ++jj) {
        ushort4 cv = make_ushort4(f2bf(vals[0][jj]), f2bf(vals[1][jj]),
                                  f2bf(vals[2][jj]), f2bf(vals[3][jj]));
        *(ushort4*)(adj_bt + base + (size_t)(j0+jj)*Nn + i0) = cv;
    }
}

// ============ K3: a2 = adj @ adj (MFMA, 64x64 tile, BK=64, reg double-buffer) ============
__global__ __launch_bounds__(256) void k_mm1(
    const unsigned short* __restrict__ adj_b, const unsigned short* __restrict__ adj_bt,
    unsigned short* __restrict__ a2b)
{
    __shared__ unsigned short Als[64*72];
    __shared__ unsigned short Bls[64*72];
    int tid = threadIdx.x;
    int wv = __builtin_amdgcn_readfirstlane(tid >> 6);
    int lane = tid & 63;
    int b = blockIdx.z, i0 = blockIdx.y*64, j0 = blockIdx.x*64;
    size_t base = (size_t)b << 18;
    const unsigned short* Ab = adj_b + base;
    const unsigned short* Bb = adj_bt + base;
    int wm = wv >> 1, wn = wv & 1;
    int m = lane & 15, q = lane >> 4;
    int sr = tid >> 2, sc = (tid & 3)*16;
    f32x4 acc[2][2];
    #pragma unroll
    for (int mt = 0; mt < 2; ++mt)
        #pragma unroll
        for (int nt = 0; nt < 2; ++nt) acc[mt][nt] = (f32x4){0.f,0.f,0.f,0.f};
    short8 pa0, pa1, pb0, pb1;
    pa0 = *(const short8*)(Ab + (size_t)(i0+sr)*Nn + sc);
    pa1 = *(const short8*)(Ab + (size_t)(i0+sr)*Nn + sc + 8);
    pb0 = *(const short8*)(Bb + (size_t)(j0+sr)*Nn + sc);
    pb1 = *(const short8*)(Bb + (size_t)(j0+sr)*Nn + sc + 8);
    for (int kt = 0; kt < 8; ++kt) {
        *(short8*)&Als[sr*72 + sc]     = pa0;
        *(short8*)&Als[sr*72 + sc + 8] = pa1;
        *(short8*)&Bls[sr*72 + sc]     = pb0;
        *(short8*)&Bls[sr*72 + sc + 8] = pb1;
        __syncthreads();
        if (kt < 7) {
            int k0 = (kt+1)*64;
            pa0 = *(const short8*)(Ab + (size_t)(i0+sr)*Nn + k0 + sc);
            pa1 = *(const short8*)(Ab + (size_t)(i0+sr)*Nn + k0 + sc + 8);
            pb0 = *(const short8*)(Bb + (size_t)(j0+sr)*Nn + k0 + sc);
            pb1 = *(const short8*)(Bb + (size_t)(j0+sr)*Nn + k0 + sc + 8);
        }
        #pragma unroll
        for (int ks = 0; ks < 2; ++ks) {
            short8 af[2], bg[2];
            #pragma unroll
            for (int mt = 0; mt < 2; ++mt) af[mt] = *(const short8*)&Als[(wm*32+mt*16+m)*72 + ks*32 + q*8];
            #pragma unroll
            for (int nt = 0; nt < 2; ++nt) bg[nt] = *(const short8*)&Bls[(wn*32+nt*16+m)*72 + ks*32 + q*8];
            #pragma unroll
            for (int mt = 0; mt < 2; ++mt)
                #pragma unroll
                for (int nt = 0; nt < 2; ++nt)
                    acc[mt][nt] = __builtin_amdgcn_mfma_f32_16x16x32_bf16(af[mt], bg[nt], acc[mt][nt], 0, 0, 0);
        }
        __syncthreads();
    }
    int col = lane & 15, rq = lane >> 4;
    #pragma unroll
    for (int mt = 0; mt < 2; ++mt)
        #pragma unroll
        for (int nt = 0; nt < 2; ++nt)
            #pragma unroll
            for (int reg = 0; reg < 4; ++reg) {
                int i = i0 + wm*32 + mt*16 + rq*4 + reg;
                int j = j0 + wn*32 + nt*16 + col;
                a2b[base + (size_t)i*Nn + j] = f2bf(acc[mt][nt][reg]);
            }
}

// ============ K4: out = adj + 0.5*a2 + 0.25*(a2@adj), + per-batch max ============
__global__ __launch_bounds__(256) void k_mm2(
    const unsigned short* __restrict__ adj_b, const unsigned short* __restrict__ adj_bt,
    const unsigned short* __restrict__ a2b,
    float* __restrict__ out, unsigned int* __restrict__ maxslot)
{
    __shared__ unsigned short Als[64*72];
    __shared__ unsigned short Bls[64*72];
    __shared__ float red[4];
    int tid = threadIdx.x;
    int wv = __builtin_amdgcn_readfirstlane(tid >> 6);
    int lane = tid & 63;
    int b = blockIdx.z, i0 = blockIdx.y*64, j0 = blockIdx.x*64;
    size_t base = (size_t)b << 18;
    const unsigned short* Ab = a2b + base;       // A = a2
    const unsigned short* Bb = adj_bt + base;    // B = adj (transposed layout)
    int wm = wv >> 1, wn = wv & 1;
    int m = lane & 15, q = lane >> 4;
    int sr = tid >> 2, sc = (tid & 3)*16;
    f32x4 acc[2][2];
    #pragma unroll
    for (int mt = 0; mt < 2; ++mt)
        #pragma unroll
        for (int nt = 0; nt < 2; ++nt) acc[mt][nt] = (f32x4){0.f,0.f,0.f,0.f};
    short8 pa0, pa1, pb0, pb1;
    pa0 = *(const short8*)(Ab + (size_t)(i0+sr)*Nn + sc);
    pa1 = *(const short8*)(Ab + (size_t)(i0+sr)*Nn + sc + 8);
    pb0 = *(const short8*)(Bb + (size_t)(j0+sr)*Nn + sc);
    pb1 = *(const short8*)(Bb + (size_t)(j0+sr)*Nn + sc + 8);
    for (int kt = 0; kt < 8; ++kt) {
        *(short8*)&Als[sr*72 + sc]     = pa0;
        *(short8*)&Als[sr*72 + sc + 8] = pa1;
        *(short8*)&Bls[sr*72 + sc]     = pb0;
        *(short8*)&Bls[sr*72 + sc + 8] = pb1;
        __syncthreads();
        if (kt < 7) {
            int k0 = (kt+1)*64;
            pa0 = *(const short8*)(Ab + (size_t)(i0+sr)*Nn + k0 + sc);
            pa1 = *(const short8*)(Ab + (size_t)(i0+sr)*Nn + k0 + sc + 8);
            pb0 = *(const short8*)(Bb + (size_t)(j0+sr)*Nn + k0 + sc);
            pb1 = *(const short8*)(Bb + (size_t)(j0+sr)*Nn + k0 + sc + 8);
        }
        #pragma unroll
        for (int ks = 0; ks < 2; ++ks) {
            short8 af[2], bg[2];
            #pragma unroll
            for (int mt = 0; mt < 2; ++mt) af[mt] = *(const short8*)&Als[(wm*32+mt*16+m)*72 + ks*32 + q*8];
            #pragma unroll
            for (int nt = 0; nt < 2; ++nt) bg[nt] = *(const short8*)&Bls[(wn*32+nt*16+m)*72 + ks*32 + q*8];
            #pragma unroll
            for (int mt = 0; mt < 2; ++mt)
                #pragma unroll
                for (int nt = 0; nt < 2; ++nt)
                    acc[mt][nt] = __builtin_amdgcn_mfma_f32_16x16x32_bf16(af[mt], bg[nt], acc[mt][nt], 0, 0, 0);
        }
        __syncthreads();
    }
    int col = lane & 15, rq = lane >> 4;
    float lmax = 0.f;
    const unsigned short* adjp = adj_b + base;
    #pragma unroll
    for (int mt = 0; mt < 2; ++mt)
        #pragma unroll
        for (int nt = 0; nt < 2; ++nt)
            #pragma unroll
            for (int reg = 0; reg < 4; ++reg) {
                int i = i0 + wm*32 + mt*16 + rq*4 + reg;
                int j = j0 + wn*32 + nt*16 + col;
                size_t off = (size_t)i*Nn + j;
                float e = bf2f(adjp[off]) + 0.5f*bf2f(Ab[off]) + 0.25f*acc[mt][nt][reg];
                out[base + off] = e;
                lmax = fmaxf(lmax, e);
            }
    #pragma unroll
    for (int s = 1; s < 64; s <<= 1) lmax = fmaxf(lmax, __shfl_xor(lmax, s, 64));
    if (lane == 0) red[wv] = lmax;
    __syncthreads();
    if (tid == 0) {
        float mx = fmaxf(fmaxf(red[0], red[1]), fmaxf(red[2], red[3]));
        atomicMax(maxslot + b, __float_as_uint(mx));
    }
}

// ============ K5: out /= (max + 1e-8) ============
__global__ __launch_bounds__(256) void k_norm(float* __restrict__ out,
                                              const unsigned int* __restrict__ maxslot)
{
    int idx = blockIdx.x*256 + threadIdx.x;   // float4 index; 65536 per batch
    int b = idx >> 16;
    float m = __uint_as_float(maxslot[b]);
    float inv = 1.f/(m + 1e-8f);
    float4* p = (float4*)out + idx;
    float4 v = *p;
    v.x *= inv; v.y *= inv; v.z *= inv; v.w *= inv;
    *p = v;
}

extern "C" void kernel_launch(void* const* d_in, const int* in_sizes, int n_in,
                              void* d_out, int out_size, void* d_ws, size_t ws_size,
                              hipStream_t stream) {
    const float* x   = (const float*)d_in[0];
    const float* W1  = (const float*)d_in[1];
    const float* b1  = (const float*)d_in[2];
    const float* W2  = (const float*)d_in[3];
    const float* b2  = (const float*)d_in[4];
    const float* Ws1 = (const float*)d_in[5];
    const float* bs1 = (const float*)d_in[6];
    const float* Ws2 = (const float*)d_in[7];
    const float* bs2 = (const float*)d_in[8];
    float* out = (float*)d_out;

    unsigned char* wsb = (unsigned char*)d_ws;
    unsigned short* spb    = (unsigned short*)(wsb);                    // 512 KB
    unsigned short* tpb    = (unsigned short*)(wsb + (512u<<10));       // 512 KB
    unsigned short* adj_b  = (unsigned short*)(wsb + (1024u<<10));      // 2 MB
    unsigned short* adj_bt = (unsigned short*)(wsb + (3072u<<10));      // 2 MB
    unsigned short* a2b    = (unsigned short*)(wsb + (5120u<<10));      // 2 MB
    unsigned int*   maxslot= (unsigned int*)(wsb + (7168u<<10));        // 16 B
    unsigned short* hb     = (unsigned short*)(wsb + (7172u<<10));      // 1 MB  [row][256]
    unsigned short* aggb   = (unsigned short*)(wsb + (8196u<<10));      // 512 KB [row][128]

    k_enc_a<<<dim3(64, 4),   256, 0, stream>>>(x, W1, b1, hb, maxslot);
    k_enc_b<<<dim3(64, 2),   256, 0, stream>>>(hb, W2, b2, aggb);
    k_enc_c<<<dim3(64, 2),   256, 0, stream>>>(aggb, Ws1, bs1, spb, tpb);
    k_score<<<dim3(8, 8, Bn),256, 0, stream>>>(spb, tpb, Ws2, bs2, adj_b, adj_bt);
    k_mm1  <<<dim3(8, 8, Bn),256, 0, stream>>>(adj_b, adj_bt, a2b);
    k_mm2  <<<dim3(8, 8, Bn),256, 0, stream>>>(adj_b, adj_bt, a2b, out, maxslot);
    k_norm <<<dim3(1024),    256, 0, stream>>>(out, maxslot);
}

// Round 15
// 122.786 us; speedup vs baseline: 3.0263x; 1.0152x over previous
//
#include <hip/hip_runtime.h>
#include <math.h>

#define Bn 4
#define Tn 12
#define Nn 512
#define Dn 128
#define Ln 4
#define Hn 64
#define NNe (Nn*Nn)

typedef __attribute__((ext_vector_type(8))) short short8;
typedef __attribute__((ext_vector_type(4))) float f32x4;

__device__ __forceinline__ unsigned short f2bf(float f) {
    unsigned int u = __float_as_uint(f);
    unsigned int r = (u + 0x7FFF + ((u >> 16) & 1)) >> 16;   // RNE
    return (unsigned short)r;
}
__device__ __forceinline__ float bf2f(unsigned short s) {
    return __uint_as_float(((unsigned int)s) << 16);
}

// ============ K1a: h[r][lag*64+n] = relu(x_lag @ W1[lag] + b1[lag]) (MFMA) ============
// Unchanged from R14 (proven: no spill, ~0 conflicts). Grid (64,4) = 256 blocks.
__global__ __launch_bounds__(256) void k_enc_a(
    const float* __restrict__ x, const float* __restrict__ W1, const float* __restrict__ b1,
    unsigned short* __restrict__ hb, unsigned int* __restrict__ maxslot)
{
    __shared__ __align__(16) unsigned short xA[32*136];   // A-tile [m=32][k=128]
    __shared__ __align__(16) unsigned short w1T[64*136];  // B-tile [n=64][k=128]
    int tid = threadIdx.x;
    int rg = blockIdx.x, lag = blockIdx.y;
    if (rg == 0 && lag == 0 && tid < Bn) maxslot[tid] = 0u;
    int r0 = rg * 32;                     // 32 rows, never straddles a batch
    int bb = r0 >> 9, n0 = r0 & 511;

    {   // stage x tile: 32 contiguous rows fp32 -> bf16 (coalesced f4 reads)
        const float4* xs = (const float4*)(x + ((size_t)(bb*Tn + (Tn-1-lag))*Nn + n0)*Dn);
        for (int v = tid; v < 1024; v += 256) {
            float4 f = xs[v];
            int row = v >> 5, c4 = v & 31;
            ushort4 o = { f2bf(f.x), f2bf(f.y), f2bf(f.z), f2bf(f.w) };
            *(ushort4*)&xA[row*136 + c4*4] = o;
        }
    }
    {   // stage W1[lag]^T: thread owns (n, k-octet); 8 coalesced scalar reads + 1 b128 write
        int n = tid & 63, kq = tid >> 6;
        const float* Wp = W1 + (size_t)lag*Dn*Hn;
        #pragma unroll
        for (int r = 0; r < 4; ++r) {
            int k0 = (r*4 + kq)*8;
            unsigned short tmp[8];
            #pragma unroll
            for (int j = 0; j < 8; ++j) tmp[j] = f2bf(Wp[(size_t)(k0+j)*Hn + n]);
            *(short8*)&w1T[n*136 + k0] = *(const short8*)tmp;
        }
    }
    __syncthreads();

    int wv = __builtin_amdgcn_readfirstlane(tid >> 6);
    int lane = tid & 63;
    int wm = wv >> 1, wn = wv & 1;
    int m = lane & 15, q = lane >> 4;
    f32x4 acc[2] = {{0.f,0.f,0.f,0.f},{0.f,0.f,0.f,0.f}};
    #pragma unroll
    for (int ks = 0; ks < 4; ++ks) {
        short8 af = *(const short8*)&xA[(wm*16 + m)*136 + ks*32 + q*8];
        #pragma unroll
        for (int nt = 0; nt < 2; ++nt) {
            short8 bg = *(const short8*)&w1T[(wn*32 + nt*16 + m)*136 + ks*32 + q*8];
            acc[nt] = __builtin_amdgcn_mfma_f32_16x16x32_bf16(af, bg, acc[nt], 0, 0, 0);
        }
    }
    int colL = lane & 15, rq = lane >> 4;
    #pragma unroll
    for (int nt = 0; nt < 2; ++nt) {
        int ncol = wn*32 + nt*16 + colL;
        float bv = b1[lag*Hn + ncol];
        #pragma unroll
        for (int reg = 0; reg < 4; ++reg) {
            int rowL = wm*16 + rq*4 + reg;
            hb[(size_t)(r0+rowL)*256 + lag*64 + ncol] = f2bf(fmaxf(acc[nt][reg] + bv, 0.f));
        }
    }
}

// ============ K1bc: agg = 0.25*(h@W2stacked + sum b2) then sp/tp = agg@Ws1 (fused) ============
// Block owns 16 rows end-to-end through LDS (agg is row-local): removes the enc_b->enc_c
// dispatch gap AND the aggb global round-trip. Grid 128. LDS 47.6 KB.
__global__ __launch_bounds__(256) void k_enc_bc(
    const unsigned short* __restrict__ hb, const float* __restrict__ W2,
    const float* __restrict__ b2, const float* __restrict__ Ws1,
    const float* __restrict__ bs1,
    unsigned short* __restrict__ spb, unsigned short* __restrict__ tpb)
{
    __shared__ __align__(16) unsigned short hA[16*264];    // A-tile [m=16][k=256]  8448 B
    __shared__ __align__(16) unsigned short wT[64*264];    // B-tile union: w2T 64x264 / wsT 128x136 (34816 B)
    __shared__ __align__(16) unsigned short aggA[16*136];  // A-tile [m=16][k=128]  4352 B
    int tid = threadIdx.x;
    int wv = __builtin_amdgcn_readfirstlane(tid >> 6);
    int lane = tid & 63;
    int r0 = blockIdx.x * 16;             // 16 rows, never straddles a batch

    for (int v = tid; v < 512; v += 256) {   // stage hA: 16 rows x 256 bf16, b128
        int row = v >> 5, c = v & 31;
        *(short8*)&hA[row*264 + c*8] = *(const short8*)(hb + (size_t)(r0+row)*256 + c*8);
    }

    int m = lane & 15, q = lane >> 4;
    int colL = lane & 15, rq = lane >> 4;

    // ---- Phase B: aggA = 0.25*(hA @ W2stacked + sum_l b2[l]), two 64-col chunks ----
    for (int ch = 0; ch < 2; ++ch) {
        __syncthreads();                  // prev wT readers done (also covers hA staging at ch=0)
        {   // stage w2T [n=64][k=256]: register transpose, b128 writes
            int n = tid & 63, kq = tid >> 6;
            #pragma unroll
            for (int r = 0; r < 8; ++r) {
                int k0 = (r*4 + kq)*8;
                unsigned short tmp[8];
                #pragma unroll
                for (int j = 0; j < 8; ++j) tmp[j] = f2bf(W2[(size_t)(k0+j)*Dn + ch*64 + n]);
                *(short8*)&wT[n*264 + k0] = *(const short8*)tmp;
            }
        }
        __syncthreads();
        f32x4 acc = {0.f,0.f,0.f,0.f};    // wave = 16-col N-tile; all waves share the 16-row M-tile
        #pragma unroll
        for (int ks = 0; ks < 8; ++ks) {
            short8 af = *(const short8*)&hA[m*264 + ks*32 + q*8];
            short8 bg = *(const short8*)&wT[(wv*16 + m)*264 + ks*32 + q*8];
            acc = __builtin_amdgcn_mfma_f32_16x16x32_bf16(af, bg, acc, 0, 0, 0);
        }
        int col = ch*64 + wv*16 + colL;
        float b2s = b2[col] + b2[Dn+col] + b2[2*Dn+col] + b2[3*Dn+col];
        #pragma unroll
        for (int reg = 0; reg < 4; ++reg)
            aggA[(rq*4+reg)*136 + col] = f2bf(0.25f*(acc[reg] + b2s));
    }

    // ---- Phase C: sp = aggA@Ws1[:D]+bs1 ; tp = aggA@Ws1[D:] ----
    for (int tgt = 0; tgt < 2; ++tgt) {
        __syncthreads();                  // aggA writes / prev wsT readers done
        {   // stage wsT [n=128][k=128]: register transpose
            int n = tid & 127, kq = tid >> 7;
            #pragma unroll
            for (int r = 0; r < 8; ++r) {
                int k0 = (r*2 + kq)*8;
                unsigned short tmp[8];
                #pragma unroll
                for (int j = 0; j < 8; ++j)
                    tmp[j] = f2bf(Ws1[(size_t)(tgt*Dn + k0 + j)*Dn + n]);
                *(short8*)&wT[n*136 + k0] = *(const short8*)tmp;
            }
        }
        __syncthreads();
        f32x4 acc[2] = {{0.f,0.f,0.f,0.f},{0.f,0.f,0.f,0.f}};   // wave = 32-col range, 2 N-tiles
        #pragma unroll
        for (int ks = 0; ks < 4; ++ks) {
            short8 af = *(const short8*)&aggA[m*136 + ks*32 + q*8];
            #pragma unroll
            for (int nt = 0; nt < 2; ++nt) {
                short8 bg = *(const short8*)&wT[(wv*32 + nt*16 + m)*136 + ks*32 + q*8];
                acc[nt] = __builtin_amdgcn_mfma_f32_16x16x32_bf16(af, bg, acc[nt], 0, 0, 0);
            }
        }
        unsigned short* dst = tgt ? tpb : spb;
        #pragma unroll
        for (int nt = 0; nt < 2; ++nt) {
            int n = wv*32 + nt*16 + colL;
            float bv = tgt ? 0.f : bs1[n];         // fold bs1 into sp
            #pragma unroll
            for (int reg = 0; reg < 4; ++reg)
                dst[(size_t)(r0 + rq*4 + reg)*Dn + n] = f2bf(acc[nt][reg] + bv);
        }
    }
}

// ============ K2: pairwise scorer -> adj bf16 row-major + transposed ============
__global__ __launch_bounds__(256) void k_score(
    const unsigned short* __restrict__ spb, const unsigned short* __restrict__ tpb,
    const float* __restrict__ Ws2, const float* __restrict__ bs2,
    unsigned short* __restrict__ adj_b, unsigned short* __restrict__ adj_bt)
{
    __shared__ float spl[64*132];                     // 33 KB
    __shared__ unsigned short tplT[Dn*72];            // 18 KB
    int tid = threadIdx.x;
    int wv = __builtin_amdgcn_readfirstlane(tid >> 6);
    int lane = tid & 63;
    int bz = blockIdx.z;
    int i0b = blockIdx.y * 64, j0b = blockIdx.x * 64;
    const unsigned short* spr = spb + (size_t)bz*Nn*Dn;
    const unsigned short* tpr = tpb + (size_t)bz*Nn*Dn;

    for (int v = tid; v < 1024; v += 256) {           // sp tile: bf16 -> fp32 LDS
        int row = v >> 4, c = v & 15;
        const unsigned short* src = spr + (size_t)(i0b+row)*Dn + c*8;
        ushort4 u0 = *(const ushort4*)src;
        ushort4 u1 = *(const ushort4*)(src + 4);
        float4 f0 = { bf2f(u0.x), bf2f(u0.y), bf2f(u0.z), bf2f(u0.w) };
        float4 f1 = { bf2f(u1.x), bf2f(u1.y), bf2f(u1.z), bf2f(u1.w) };
        *(float4*)&spl[row*132 + c*8]     = f0;
        *(float4*)&spl[row*132 + c*8 + 4] = f1;
    }
    {   // tp tile transposed, bf16
        int j = tid & 63, kq = tid >> 6;
        for (int p = 0; p < 4; ++p) {
            int k8 = p*4 + kq;
            short8 tv = *(const short8*)(tpr + (size_t)(j0b+j)*Dn + k8*8);
            #pragma unroll
            for (int t = 0; t < 8; ++t) tplT[(k8*8+t)*72 + j] = (unsigned short)tv[t];
        }
    }
    __syncthreads();

    int iq = lane >> 4, jq = lane & 15;
    int iw = wv*16 + iq*4;
    float acc[4][4] = {};
    for (int k8 = 0; k8 < 16; ++k8) {
        float4 wa = *(const float4*)(Ws2 + k8*8);     // uniform -> scalar path
        float4 wb = *(const float4*)(Ws2 + k8*8 + 4);
        float4 sA[4], sB[4];
        #pragma unroll
        for (int ii = 0; ii < 4; ++ii) {
            sA[ii] = *(const float4*)&spl[(iw+ii)*132 + k8*8];
            sB[ii] = *(const float4*)&spl[(iw+ii)*132 + k8*8 + 4];
        }
        ushort4 t4[8];
        #pragma unroll
        for (int kk = 0; kk < 8; ++kk) t4[kk] = *(const ushort4*)&tplT[(k8*8+kk)*72 + jq*4];
        #pragma unroll
        for (int kk = 0; kk < 8; ++kk) {
            float w = (kk < 4) ? ((const float*)&wa)[kk] : ((const float*)&wb)[kk-4];
            float tv0 = bf2f(t4[kk].x), tv1 = bf2f(t4[kk].y);
            float tv2 = bf2f(t4[kk].z), tv3 = bf2f(t4[kk].w);
            #pragma unroll
            for (int ii = 0; ii < 4; ++ii) {
                float s = (kk < 4) ? ((const float*)&sA[ii])[kk] : ((const float*)&sB[ii])[kk-4];
                acc[ii][0] += fmaxf(s + tv0, 0.f)*w;
                acc[ii][1] += fmaxf(s + tv1, 0.f)*w;
                acc[ii][2] += fmaxf(s + tv2, 0.f)*w;
                acc[ii][3] += fmaxf(s + tv3, 0.f)*w;
            }
        }
    }
    float bsv = bs2[0];
    int i0 = i0b + iw;
    int j0 = j0b + jq*4;
    float vals[4][4];
    #pragma unroll
    for (int ii = 0; ii < 4; ++ii) {
        int i = i0 + ii;
        #pragma unroll
        for (int jj = 0; jj < 4; ++jj) {
            float z = acc[ii][jj] + bsv;
            float sc = 1.f/(1.f + __expf(-z));
            int j = j0 + jj;
            vals[ii][jj] = (sc > 0.1f && i != j) ? sc : 0.f;
        }
    }
    size_t base = (size_t)bz << 18;
    #pragma unroll
    for (int ii = 0; ii < 4; ++ii) {
        ushort4 rv = make_ushort4(f2bf(vals[ii][0]), f2bf(vals[ii][1]),
                                  f2bf(vals[ii][2]), f2bf(vals[ii][3]));
        *(ushort4*)(adj_b + base + (size_t)(i0+ii)*Nn + j0) = rv;
    }
    #pragma unroll
    for (int jj = 0; jj < 4; ++jj) {
        ushort4 cv = make_ushort4(f2bf(vals[0][jj]), f2bf(vals[1][jj]),
                                  f2bf(vals[2][jj]), f2bf(vals[3][jj]));
        *(ushort4*)(adj_bt + base + (size_t)(j0+jj)*Nn + i0) = cv;
    }
}

// ============ K3: a2 = adj @ adj (MFMA, 64x64 tile, BK=64, reg double-buffer) ============
__global__ __launch_bounds__(256) void k_mm1(
    const unsigned short* __restrict__ adj_b, const unsigned short* __restrict__ adj_bt,
    unsigned short* __restrict__ a2b)
{
    __shared__ unsigned short Als[64*72];
    __shared__ unsigned short Bls[64*72];
    int tid = threadIdx.x;
    int wv = __builtin_amdgcn_readfirstlane(tid >> 6);
    int lane = tid & 63;
    int b = blockIdx.z, i0 = blockIdx.y*64, j0 = blockIdx.x*64;
    size_t base = (size_t)b << 18;
    const unsigned short* Ab = adj_b + base;
    const unsigned short* Bb = adj_bt + base;
    int wm = wv >> 1, wn = wv & 1;
    int m = lane & 15, q = lane >> 4;
    int sr = tid >> 2, sc = (tid & 3)*16;
    f32x4 acc[2][2];
    #pragma unroll
    for (int mt = 0; mt < 2; ++mt)
        #pragma unroll
        for (int nt = 0; nt < 2; ++nt) acc[mt][nt] = (f32x4){0.f,0.f,0.f,0.f};
    short8 pa0, pa1, pb0, pb1;
    pa0 = *(const short8*)(Ab + (size_t)(i0+sr)*Nn + sc);
    pa1 = *(const short8*)(Ab + (size_t)(i0+sr)*Nn + sc + 8);
    pb0 = *(const short8*)(Bb + (size_t)(j0+sr)*Nn + sc);
    pb1 = *(const short8*)(Bb + (size_t)(j0+sr)*Nn + sc + 8);
    for (int kt = 0; kt < 8; ++kt) {
        *(short8*)&Als[sr*72 + sc]     = pa0;
        *(short8*)&Als[sr*72 + sc + 8] = pa1;
        *(short8*)&Bls[sr*72 + sc]     = pb0;
        *(short8*)&Bls[sr*72 + sc + 8] = pb1;
        __syncthreads();
        if (kt < 7) {
            int k0 = (kt+1)*64;
            pa0 = *(const short8*)(Ab + (size_t)(i0+sr)*Nn + k0 + sc);
            pa1 = *(const short8*)(Ab + (size_t)(i0+sr)*Nn + k0 + sc + 8);
            pb0 = *(const short8*)(Bb + (size_t)(j0+sr)*Nn + k0 + sc);
            pb1 = *(const short8*)(Bb + (size_t)(j0+sr)*Nn + k0 + sc + 8);
        }
        #pragma unroll
        for (int ks = 0; ks < 2; ++ks) {
            short8 af[2], bg[2];
            #pragma unroll
            for (int mt = 0; mt < 2; ++mt) af[mt] = *(const short8*)&Als[(wm*32+mt*16+m)*72 + ks*32 + q*8];
            #pragma unroll
            for (int nt = 0; nt < 2; ++nt) bg[nt] = *(const short8*)&Bls[(wn*32+nt*16+m)*72 + ks*32 + q*8];
            #pragma unroll
            for (int mt = 0; mt < 2; ++mt)
                #pragma unroll
                for (int nt = 0; nt < 2; ++nt)
                    acc[mt][nt] = __builtin_amdgcn_mfma_f32_16x16x32_bf16(af[mt], bg[nt], acc[mt][nt], 0, 0, 0);
        }
        __syncthreads();
    }
    int col = lane & 15, rq = lane >> 4;
    #pragma unroll
    for (int mt = 0; mt < 2; ++mt)
        #pragma unroll
        for (int nt = 0; nt < 2; ++nt)
            #pragma unroll
            for (int reg = 0; reg < 4; ++reg) {
                int i = i0 + wm*32 + mt*16 + rq*4 + reg;
                int j = j0 + wn*32 + nt*16 + col;
                a2b[base + (size_t)i*Nn + j] = f2bf(acc[mt][nt][reg]);
            }
}

// ============ K4: out = adj + 0.5*a2 + 0.25*(a2@adj), + per-batch max ============
__global__ __launch_bounds__(256) void k_mm2(
    const unsigned short* __restrict__ adj_b, const unsigned short* __restrict__ adj_bt,
    const unsigned short* __restrict__ a2b,
    float* __restrict__ out, unsigned int* __restrict__ maxslot)
{
    __shared__ unsigned short Als[64*72];
    __shared__ unsigned short Bls[64*72];
    __shared__ float red[4];
    int tid = threadIdx.x;
    int wv = __builtin_amdgcn_readfirstlane(tid >> 6);
    int lane = tid & 63;
    int b = blockIdx.z, i0 = blockIdx.y*64, j0 = blockIdx.x*64;
    size_t base = (size_t)b << 18;
    const unsigned short* Ab = a2b + base;       // A = a2
    const unsigned short* Bb = adj_bt + base;    // B = adj (transposed layout)
    int wm = wv >> 1, wn = wv & 1;
    int m = lane & 15, q = lane >> 4;
    int sr = tid >> 2, sc = (tid & 3)*16;
    f32x4 acc[2][2];
    #pragma unroll
    for (int mt = 0; mt < 2; ++mt)
        #pragma unroll
        for (int nt = 0; nt < 2; ++nt) acc[mt][nt] = (f32x4){0.f,0.f,0.f,0.f};
    short8 pa0, pa1, pb0, pb1;
    pa0 = *(const short8*)(Ab + (size_t)(i0+sr)*Nn + sc);
    pa1 = *(const short8*)(Ab + (size_t)(i0+sr)*Nn + sc + 8);
    pb0 = *(const short8*)(Bb + (size_t)(j0+sr)*Nn + sc);
    pb1 = *(const short8*)(Bb + (size_t)(j0+sr)*Nn + sc + 8);
    for (int kt = 0; kt < 8; ++kt) {
        *(short8*)&Als[sr*72 + sc]     = pa0;
        *(short8*)&Als[sr*72 + sc + 8] = pa1;
        *(short8*)&Bls[sr*72 + sc]     = pb0;
        *(short8*)&Bls[sr*72 + sc + 8] = pb1;
        __syncthreads();
        if (kt < 7) {
            int k0 = (kt+1)*64;
            pa0 = *(const short8*)(Ab + (size_t)(i0+sr)*Nn + k0 + sc);
            pa1 = *(const short8*)(Ab + (size_t)(i0+sr)*Nn + k0 + sc + 8);
            pb0 = *(const short8*)(Bb + (size_t)(j0+sr)*Nn + k0 + sc);
            pb1 = *(const short8*)(Bb + (size_t)(j0+sr)*Nn + k0 + sc + 8);
        }
        #pragma unroll
        for (int ks = 0; ks < 2; ++ks) {
            short8 af[2], bg[2];
            #pragma unroll
            for (int mt = 0; mt < 2; ++mt) af[mt] = *(const short8*)&Als[(wm*32+mt*16+m)*72 + ks*32 + q*8];
            #pragma unroll
            for (int nt = 0; nt < 2; ++nt) bg[nt] = *(const short8*)&Bls[(wn*32+nt*16+m)*72 + ks*32 + q*8];
            #pragma unroll
            for (int mt = 0; mt < 2; ++mt)
                #pragma unroll
                for (int nt = 0; nt < 2; ++nt)
                    acc[mt][nt] = __builtin_amdgcn_mfma_f32_16x16x32_bf16(af[mt], bg[nt], acc[mt][nt], 0, 0, 0);
        }
        __syncthreads();
    }
    int col = lane & 15, rq = lane >> 4;
    float lmax = 0.f;
    const unsigned short* adjp = adj_b + base;
    #pragma unroll
    for (int mt = 0; mt < 2; ++mt)
        #pragma unroll
        for (int nt = 0; nt < 2; ++nt)
            #pragma unroll
            for (int reg = 0; reg < 4; ++reg) {
                int i = i0 + wm*32 + mt*16 + rq*4 + reg;
                int j = j0 + wn*32 + nt*16 + col;
                size_t off = (size_t)i*Nn + j;
                float e = bf2f(adjp[off]) + 0.5f*bf2f(Ab[off]) + 0.25f*acc[mt][nt][reg];
                out[base + off] = e;
                lmax = fmaxf(lmax, e);
            }
    #pragma unroll
    for (int s = 1; s < 64; s <<= 1) lmax = fmaxf(lmax, __shfl_xor(lmax, s, 64));
    if (lane == 0) red[wv] = lmax;
    __syncthreads();
    if (tid == 0) {
        float mx = fmaxf(fmaxf(red[0], red[1]), fmaxf(red[2], red[3]));
        atomicMax(maxslot + b, __float_as_uint(mx));
    }
}

// ============ K5: out /= (max + 1e-8) ============
__global__ __launch_bounds__(256) void k_norm(float* __restrict__ out,
                                              const unsigned int* __restrict__ maxslot)
{
    int idx = blockIdx.x*256 + threadIdx.x;   // float4 index; 65536 per batch
    int b = idx >> 16;
    float m = __uint_as_float(maxslot[b]);
    float inv = 1.f/(m + 1e-8f);
    float4* p = (float4*)out + idx;
    float4 v = *p;
    v.x *= inv; v.y *= inv; v.z *= inv; v.w *= inv;
    *p = v;
}

extern "C" void kernel_launch(void* const* d_in, const int* in_sizes, int n_in,
                              void* d_out, int out_size, void* d_ws, size_t ws_size,
                              hipStream_t stream) {
    const float* x   = (const float*)d_in[0];
    const float* W1  = (const float*)d_in[1];
    const float* b1  = (const float*)d_in[2];
    const float* W2  = (const float*)d_in[3];
    const float* b2  = (const float*)d_in[4];
    const float* Ws1 = (const float*)d_in[5];
    const float* bs1 = (const float*)d_in[6];
    const float* Ws2 = (const float*)d_in[7];
    const float* bs2 = (const float*)d_in[8];
    float* out = (float*)d_out;

    unsigned char* wsb = (unsigned char*)d_ws;
    unsigned short* spb    = (unsigned short*)(wsb);                    // 512 KB
    unsigned short* tpb    = (unsigned short*)(wsb + (512u<<10));       // 512 KB
    unsigned short* adj_b  = (unsigned short*)(wsb + (1024u<<10));      // 2 MB
    unsigned short* adj_bt = (unsigned short*)(wsb + (3072u<<10));      // 2 MB
    unsigned short* a2b    = (unsigned short*)(wsb + (5120u<<10));      // 2 MB
    unsigned int*   maxslot= (unsigned int*)(wsb + (7168u<<10));        // 16 B
    unsigned short* hb     = (unsigned short*)(wsb + (7172u<<10));      // 1 MB  [row][256]

    k_enc_a <<<dim3(64, 4),   256, 0, stream>>>(x, W1, b1, hb, maxslot);
    k_enc_bc<<<dim3(128),     256, 0, stream>>>(hb, W2, b2, Ws1, bs1, spb, tpb);
    k_score <<<dim3(8, 8, Bn),256, 0, stream>>>(spb, tpb, Ws2, bs2, adj_b, adj_bt);
    k_mm1   <<<dim3(8, 8, Bn),256, 0, stream>>>(adj_b, adj_bt, a2b);
    k_mm2   <<<dim3(8, 8, Bn),256, 0, stream>>>(adj_b, adj_bt, a2b, out, maxslot);
    k_norm  <<<dim3(1024),    256, 0, stream>>>(out, maxslot);
}